// Round 6
// baseline (755.067 us; speedup 1.0000x reference)
//
#include <hip/hip_runtime.h>
#include <math.h>

#define DD 768
#define NH 4
#define HDIM 192
#define BBATCH 8
#define NSEQ 1024
#define TLEN 2000

typedef _Float16 h16;
typedef _Float16 half8v __attribute__((ext_vector_type(8)));
typedef _Float16 half4v __attribute__((ext_vector_type(4)));
typedef float f32x4 __attribute__((ext_vector_type(4)));

__device__ __forceinline__ float gelu_f(float x){
  return 0.5f * x * (1.0f + erff(x * 0.70710678118654752440f));
}
__device__ __forceinline__ float wave_sum(float v){
  #pragma unroll
  for (int off = 32; off; off >>= 1) v += __shfl_xor(v, off);
  return v;
}
__device__ __forceinline__ float wave_max(float v){
  #pragma unroll
  for (int off = 32; off; off >>= 1) v = fmaxf(v, __shfl_xor(v, off));
  return v;
}
__device__ __forceinline__ void gload16(const h16* g, h16* l){
  __builtin_amdgcn_global_load_lds(
      (const __attribute__((address_space(1))) void*)g,
      (__attribute__((address_space(3))) void*)l, 16, 0, 0);
}

// ---------------- f32 -> f16 cast ----------------
__global__ __launch_bounds__(256) void k_cast(const float* __restrict__ s,
    h16* __restrict__ d, int n){
  int i = blockIdx.x * 256 + threadIdx.x;
  if (i < n) d[i] = (h16)s[i];
}

// ---------------- conv1 (20->128, k=3) + bn + gelu, LDS tiled ----------------
__global__ __launch_bounds__(256) void k_conv1t(const float* __restrict__ cqcc,
    const float* __restrict__ w, const float* __restrict__ bias,
    const float* __restrict__ g, const float* __restrict__ be,
    const float* __restrict__ mm, const float* __restrict__ vv,
    float* __restrict__ out){
  __shared__ float xs[20][258];
  __shared__ float wsm[32*60];
  const int t0 = blockIdx.x * 256;
  const int ocg = blockIdx.y, b = blockIdx.z;
  const int tid = threadIdx.x;
  for (int idx = tid; idx < 20*258; idx += 256){
    int ic = idx / 258, tt = idx % 258;
    int t = t0 + tt - 1;
    xs[ic][tt] = (t >= 0 && t < TLEN) ? cqcc[((size_t)b*20 + ic)*TLEN + t] : 0.f;
  }
  for (int idx = tid; idx < 32*60; idx += 256)
    wsm[idx] = w[ocg*32*60 + idx];
  __syncthreads();
  int t = t0 + tid;
  if (t >= TLEN) return;
  float acc[32] = {};
  for (int ic = 0; ic < 20; ++ic){
    float x0 = xs[ic][tid], x1v = xs[ic][tid+1], x2v = xs[ic][tid+2];
    #pragma unroll
    for (int oc = 0; oc < 32; ++oc){
      const float* wp = &wsm[(oc*20 + ic)*3];
      acc[oc] += wp[0]*x0 + wp[1]*x1v + wp[2]*x2v;
    }
  }
  #pragma unroll 4
  for (int oc = 0; oc < 32; ++oc){
    int c = ocg*32 + oc;
    float s = rsqrtf(vv[c] + 1e-5f) * g[c];
    float val = (acc[oc] + bias[c] - mm[c]) * s + be[c];
    out[((size_t)b*128 + c)*TLEN + t] = gelu_f(val);
  }
}

// ---------------- im2col for conv2: x1[b][128][2000] -> A2[16000][384] f16 ---
__global__ __launch_bounds__(256) void k_im2col(const float* __restrict__ x1,
    h16* __restrict__ A2){
  int idx = blockIdx.x * 256 + threadIdx.x;
  if (idx >= 16000*384) return;
  int c = idx % 384, m = idx / 384;
  int b = m / TLEN, t = m % TLEN;
  int ic = c / 3, kh = c % 3;
  int ts = t + kh - 1;
  float v = (ts < 0 || ts >= TLEN) ? 0.f : x1[((size_t)b*128 + ic)*TLEN + ts];
  A2[idx] = (h16)v;
}

// ---------------- BN epilogue constants for conv2 ----------------
__global__ void k_bnprep(const float* __restrict__ cb, const float* __restrict__ g,
    const float* __restrict__ be, const float* __restrict__ m,
    const float* __restrict__ v, float* __restrict__ sc, float* __restrict__ off){
  int i = blockIdx.x * 256 + threadIdx.x;
  if (i >= DD) return;
  float s = g[i] * rsqrtf(v[i] + 1e-5f);
  sc[i] = s;
  off[i] = (cb[i] - m[i]) * s + be[i];
}

// ---------------- interp (2000->1024) on [b][t][768] layout + pos ----------
__global__ __launch_bounds__(256) void k_interp2(const float* __restrict__ x2,
    const float* __restrict__ pe, float* __restrict__ cq){
  int idx = blockIdx.x * 256 + threadIdx.x;
  if (idx >= BBATCH * NSEQ * DD) return;
  int d = idx % DD; int i = (idx / DD) % NSEQ; int b = idx / (DD * NSEQ);
  float p = (i + 0.5f) * ((float)TLEN / (float)NSEQ) - 0.5f;
  p = fminf(fmaxf(p, 0.f), (float)(TLEN - 1));
  int lo = (int)floorf(p);
  int hi = min(lo + 1, TLEN - 1);
  float w = p - (float)lo;
  const float* base = x2 + (size_t)b * TLEN * DD + d;
  float val = base[(size_t)lo * DD] * (1.f - w) + base[(size_t)hi * DD] * w;
  cq[idx] = val + pe[(size_t)i * DD + d];
}

__global__ __launch_bounds__(256) void k_addpos(const float* __restrict__ x,
    const float* __restrict__ pe, float* __restrict__ y){
  int idx = blockIdx.x * 256 + threadIdx.x;
  if (idx >= BBATCH * NSEQ * DD) return;
  int d = idx % DD; int i = (idx / DD) % NSEQ;
  y[idx] = x[idx] + pe[(size_t)i * DD + d];
}

// ---------------- layernorm 768, optional ctx add, f32+f16 outputs ----------
__global__ __launch_bounds__(256) void k_ln2(const float* __restrict__ in,
    const float* __restrict__ ctx, const float* __restrict__ g,
    const float* __restrict__ be, float* __restrict__ outf, h16* __restrict__ outh){
  __shared__ float ss[4], sqq[4];
  int row = blockIdx.x, tid = threadIdx.x;
  const float* ip = in + (size_t)row * DD;
  int b = row >> 10;
  float v[3]; float s = 0.f, sq = 0.f;
  #pragma unroll
  for (int j = 0; j < 3; ++j){
    int d = j * 256 + tid;
    float x = ip[d];
    if (ctx) x += ctx[b * DD + d];
    v[j] = x; s += x; sq += x * x;
  }
  s = wave_sum(s); sq = wave_sum(sq);
  int w = tid >> 6;
  if ((tid & 63) == 0){ ss[w] = s; sqq[w] = sq; }
  __syncthreads();
  s  = ss[0] + ss[1] + ss[2] + ss[3];
  sq = sqq[0] + sqq[1] + sqq[2] + sqq[3];
  float mean = s * (1.f / DD);
  float var  = sq * (1.f / DD) - mean * mean;
  float r = rsqrtf(var + 1e-5f);
  #pragma unroll
  for (int j = 0; j < 3; ++j){
    int d = j * 256 + tid;
    float y = (v[j] - mean) * r * g[d] + be[d];
    if (outf) outf[(size_t)row * DD + d] = y;
    if (outh) outh[(size_t)row * DD + d] = (h16)y;
  }
}

// ---------------- dual layernorm: one read, two (g,b) variants --------------
__global__ __launch_bounds__(256) void k_ln2two(const float* __restrict__ in,
    const float* __restrict__ g1, const float* __restrict__ b1, h16* __restrict__ o1,
    const float* __restrict__ g2, const float* __restrict__ b2, h16* __restrict__ o2){
  __shared__ float ss[4], sqq[4];
  int row = blockIdx.x, tid = threadIdx.x;
  const float* ip = in + (size_t)row * DD;
  float v[3]; float s = 0.f, sq = 0.f;
  #pragma unroll
  for (int j = 0; j < 3; ++j){
    int d = j * 256 + tid;
    float x = ip[d];
    v[j] = x; s += x; sq += x * x;
  }
  s = wave_sum(s); sq = wave_sum(sq);
  int w = tid >> 6;
  if ((tid & 63) == 0){ ss[w] = s; sqq[w] = sq; }
  __syncthreads();
  s  = ss[0] + ss[1] + ss[2] + ss[3];
  sq = sqq[0] + sqq[1] + sqq[2] + sqq[3];
  float mean = s * (1.f / DD);
  float var  = sq * (1.f / DD) - mean * mean;
  float r = rsqrtf(var + 1e-5f);
  #pragma unroll
  for (int j = 0; j < 3; ++j){
    int d = j * 256 + tid;
    float xn = (v[j] - mean) * r;
    o1[(size_t)row * DD + d] = (h16)(xn * g1[d] + b1[d]);
    o2[(size_t)row * DD + d] = (h16)(xn * g2[d] + b2[d]);
  }
}

// ---------------- f16 MFMA GEMM, 128x128 tile, double-buffered ---------------
// C[M,N] = A[M,K] @ W[N,K]^T. BM=128, BN=128, BK=64, 4 waves (2x2), 64x64/wave.
template<int BN>
__global__ __launch_bounds__(256) void k_gemm_h(
    const h16* __restrict__ A, const h16* __restrict__ W,
    long long sA_hi, long long sA_lo, long long sW_hi, long long sW_lo,
    long long sC_hi, long long sC_lo,
    int lda, int ldw, int ldc, int K, int bzs,
    const float* __restrict__ bias, const float* __restrict__ sc,
    const float* __restrict__ off,
    const h16* __restrict__ addh, float* __restrict__ outf, h16* __restrict__ outh)
{
  __shared__ h16 Als[2][128*64];
  __shared__ h16 Bls[2][BN*64];
  const int tid = threadIdx.x;
  const int z = blockIdx.z, zh = z >> 2, zl = z & 3;
  const size_t aBase = (size_t)(zh * sA_hi + zl * sA_lo);
  const size_t wBase = (size_t)(zh * sW_hi + zl * sW_lo);
  const size_t cBase = (size_t)(zh * sC_hi + zl * sC_lo);
  const int n0 = blockIdx.x * BN, m0 = blockIdx.y * 128;
  const int lane = tid & 63, wid = tid >> 6;
  const int wr = wid >> 1, wc = wid & 1;
  const int lr = lane & 15, lg = lane >> 4;
  constexpr int NR = BN / 32;
  f32x4 acc[4][NR] = {};
  const h16* Ab = A + aBase;
  const h16* Wb = W + wBase;
  auto stage = [&](int buf, int kt){
    #pragma unroll
    for (int i = 0; i < 4; ++i){
      int p = i*256 + tid;
      int row = p >> 3;
      int ch = (p & 7) ^ (row & 7);
      gload16(Ab + (size_t)(m0+row)*lda + kt + ch*8, &Als[buf][p*8]);
    }
    #pragma unroll
    for (int i = 0; i < BN/32; ++i){
      int p = i*256 + tid;
      int row = p >> 3;
      int ch = (p & 7) ^ (row & 7);
      gload16(Wb + (size_t)(n0+row)*ldw + kt + ch*8, &Bls[buf][p*8]);
    }
  };
  stage(0, 0);
  __syncthreads();
  const int nk = K >> 6;
  for (int t = 0; t < nk; ++t){
    const int cur = t & 1;
    if (t + 1 < nk) stage(cur ^ 1, (t + 1) << 6);
    #pragma unroll
    for (int kk = 0; kk < 2; ++kk){
      half8v af[4], bf[NR];
      #pragma unroll
      for (int mi = 0; mi < 4; ++mi){
        int row = wr*64 + mi*16 + lr;
        int chp = (kk*4 + lg) ^ (row & 7);
        af[mi] = *(const half8v*)&Als[cur][row*64 + chp*8];
      }
      #pragma unroll
      for (int ni = 0; ni < NR; ++ni){
        int row = wc*(BN/2) + ni*16 + lr;
        int chp = (kk*4 + lg) ^ (row & 7);
        bf[ni] = *(const half8v*)&Bls[cur][row*64 + chp*8];
      }
      #pragma unroll
      for (int mi = 0; mi < 4; ++mi)
        #pragma unroll
        for (int ni = 0; ni < NR; ++ni)
          acc[mi][ni] = __builtin_amdgcn_mfma_f32_16x16x32_f16(af[mi], bf[ni], acc[mi][ni], 0, 0, 0);
    }
    __syncthreads();
  }
  #pragma unroll
  for (int mi = 0; mi < 4; ++mi){
    #pragma unroll
    for (int ni = 0; ni < NR; ++ni){
      int col = n0 + wc*(BN/2) + ni*16 + lr;
      int rowb = m0 + wr*64 + mi*16 + lg*4;
      float cb = bias ? bias[zl*bzs + col] : 0.f;
      #pragma unroll
      for (int r = 0; r < 4; ++r){
        int row = rowb + r;
        size_t idx = cBase + (size_t)row * ldc + col;
        float v = acc[mi][ni][r];
        if (sc){ v = v * sc[col] + off[col]; v = gelu_f(v); }
        else v += cb;
        if (addh) v += (float)addh[idx];
        if (outf) outf[idx] = v;
        if (outh) outh[idx] = (h16)v;
      }
    }
  }
}

// ---------------- V transpose: V[b][q][h-part] -> VT[bh][d][q] ---------------
__global__ __launch_bounds__(256) void k_trV(const h16* __restrict__ Vh, int ldv,
    h16* __restrict__ VT){
  __shared__ h16 tile[32][36];
  const int z = blockIdx.z, b = z >> 2, h = z & 3;
  const int q0 = blockIdx.x * 32, d0 = blockIdx.y * 32;
  const int t = threadIdx.x;
  {
    int qq = t >> 3, dg = (t & 7) * 4;
    const h16* src = Vh + ((size_t)b*NSEQ + q0 + qq)*ldv + h*HDIM + d0 + dg;
    half4v v = *(const half4v*)src;
    *(half4v*)&tile[qq][dg] = v;
  }
  __syncthreads();
  {
    int dd = t >> 3, qg = (t & 7) * 4;
    half4v ov;
    ov[0] = tile[qg+0][dd]; ov[1] = tile[qg+1][dd];
    ov[2] = tile[qg+2][dd]; ov[3] = tile[qg+3][dd];
    *(half4v*)(VT + (size_t)z*HDIM*NSEQ + (size_t)(d0+dd)*NSEQ + q0 + qg) = ov;
  }
}

// ---------------- fused flash attention (MFMA, online softmax) ---------------
// grid (32 bh, 16 q-tiles): XCD-local K/V (same bh -> same XCD).
// 256 threads = 4 waves x 16 q-rows. Q in registers; K/V LDS double-buffered,
// KVBLK=32. LDS 53 KB -> 3 blocks/CU capacity.
__global__ __launch_bounds__(256) void k_flash(const h16* __restrict__ Qp,
    const h16* __restrict__ Kp, const h16* __restrict__ VTp,
    h16* __restrict__ Op){
  __shared__ h16 Ks[2][32*192];
  __shared__ h16 Vs[2][192*32];
  __shared__ h16 Ps[4][16*32];
  const int tid = threadIdx.x;
  const int bh = blockIdx.x, qt = blockIdx.y;
  const int b = bh >> 2, h = bh & 3;
  const int q0 = qt * 64;
  const h16* Qg = Qp + (size_t)b*NSEQ*DD + h*HDIM;
  const h16* Kg = Kp + (size_t)b*NSEQ*1536 + h*HDIM;
  const h16* Vg = VTp + (size_t)bh*HDIM*NSEQ;
  const int lane = tid & 63, wid = tid >> 6;
  const int lr = lane & 15, lg = lane >> 4;
  half8v qf[6];
  {
    int qrow = q0 + wid*16 + lr;
    #pragma unroll
    for (int ks = 0; ks < 6; ++ks)
      qf[ks] = *(const half8v*)(Qg + (size_t)qrow*DD + ks*32 + lg*8);
  }
  auto stageK = [&](int buf, int k0){
    #pragma unroll
    for (int i = 0; i < 3; ++i){
      int p = i*256 + tid;              // 768 = 32 rows * 24 chunks
      int row = p / 24, chp = p % 24;
      int ch = chp ^ (row & 7);
      gload16(Kg + (size_t)(k0+row)*1536 + ch*8, &Ks[buf][p*8]);
    }
  };
  auto stageV = [&](int buf, int k0){
    #pragma unroll
    for (int i = 0; i < 3; ++i){
      int p = i*256 + tid;              // 768 = 192 rows * 4 chunks
      int row = p >> 2, chp = p & 3;
      int ch = chp ^ ((row >> 1) & 3);
      gload16(Vg + (size_t)row*NSEQ + k0 + ch*8, &Vs[buf][p*8]);
    }
  };
  stageK(0, 0); stageV(0, 0);
  f32x4 oacc[12] = {};
  float m_run[4] = {-1e30f, -1e30f, -1e30f, -1e30f};
  float l_run[4] = {};
  const float SC = 0.07216878364870322f;   // 1/sqrt(192)
  __syncthreads();
  for (int kt = 0; kt < 32; ++kt){
    const int cur = kt & 1;
    if (kt + 1 < 32){ stageK(cur^1, (kt+1)*32); stageV(cur^1, (kt+1)*32); }
    // S = Q @ K^T (16 q x 32 keys per wave)
    f32x4 sacc[2] = {};
    #pragma unroll
    for (int ks = 0; ks < 6; ++ks){
      #pragma unroll
      for (int t = 0; t < 2; ++t){
        int krow = t*16 + lr;
        int ch = (ks*4 + lg) ^ (krow & 7);
        half8v kf = *(const half8v*)&Ks[cur][krow*192 + ch*8];
        sacc[t] = __builtin_amdgcn_mfma_f32_16x16x32_f16(qf[ks], kf, sacc[t], 0, 0, 0);
      }
    }
    // online softmax (rows r spread across 16 lanes of group lg)
    float mnew[4], c[4], psum[4];
    #pragma unroll
    for (int r = 0; r < 4; ++r){
      float mt = fmaxf(sacc[0][r], sacc[1][r]);
      #pragma unroll
      for (int off = 1; off < 16; off <<= 1) mt = fmaxf(mt, __shfl_xor(mt, off));
      mnew[r] = fmaxf(m_run[r], mt * SC);
      c[r] = __expf(m_run[r] - mnew[r]);
      psum[r] = 0.f;
    }
    #pragma unroll
    for (int t = 0; t < 2; ++t){
      #pragma unroll
      for (int r = 0; r < 4; ++r){
        float p = __expf(sacc[t][r] * SC - mnew[r]);
        psum[r] += p;
        int q = lg*4 + r, key = t*16 + lr;
        int ch = (t*2 + (lr>>3)) ^ ((q>>1) & 3);
        Ps[wid][q*32 + ch*8 + (key & 7)] = (h16)p;
      }
    }
    #pragma unroll
    for (int r = 0; r < 4; ++r){
      #pragma unroll
      for (int off = 1; off < 16; off <<= 1) psum[r] += __shfl_xor(psum[r], off);
      l_run[r] = l_run[r] * c[r] + psum[r];
      m_run[r] = mnew[r];
    }
    #pragma unroll
    for (int dt = 0; dt < 12; ++dt){
      f32x4 o = oacc[dt];
      o[0] *= c[0]; o[1] *= c[1]; o[2] *= c[2]; o[3] *= c[3];
      oacc[dt] = o;
    }
    asm volatile("s_waitcnt lgkmcnt(0)" ::: "memory");  // own-wave P writes done
    // O += P @ V
    {
      int pch = lg ^ ((lr >> 1) & 3);
      half8v pf = *(const half8v*)&Ps[wid][lr*32 + pch*8];
      #pragma unroll
      for (int dt = 0; dt < 12; ++dt){
        int drow = dt*16 + lr;
        int vch = lg ^ ((drow >> 1) & 3);
        half8v vf = *(const half8v*)&Vs[cur][drow*32 + vch*8];
        oacc[dt] = __builtin_amdgcn_mfma_f32_16x16x32_f16(pf, vf, oacc[dt], 0, 0, 0);
      }
    }
    __syncthreads();
  }
  float inv[4];
  #pragma unroll
  for (int r = 0; r < 4; ++r) inv[r] = 1.0f / l_run[r];
  h16* Og = Op + (size_t)b*NSEQ*DD + h*HDIM;
  #pragma unroll
  for (int dt = 0; dt < 12; ++dt){
    #pragma unroll
    for (int r = 0; r < 4; ++r){
      int q = q0 + wid*16 + lg*4 + r;
      Og[(size_t)q*DD + dt*16 + lr] = (h16)(oacc[dt][r] * inv[r]);
    }
  }
}

// ---------------- GAT helpers ----------------
__global__ __launch_bounds__(128) void k_rowdot(const h16* __restrict__ h,
    const float* __restrict__ aw, float* __restrict__ sj){
  __shared__ float red[2];
  int row = blockIdx.x, tid = threadIdx.x;
  float s = 0.f;
  if (tid < 96){
    half8v v = *(const half8v*)(h + (size_t)row * DD + tid*8);
    #pragma unroll
    for (int j = 0; j < 8; ++j) s += (float)v[j] * aw[tid*8 + j];
  }
  s = wave_sum(s);
  if ((tid & 63) == 0) red[tid >> 6] = s;
  __syncthreads();
  if (tid == 0) sj[row] = red[0] + red[1];
}

__global__ __launch_bounds__(256) void k_softmax1024(const float* __restrict__ x,
    float* __restrict__ y){
  __shared__ float red[4];
  int b = blockIdx.x, tid = threadIdx.x;
  const float* ip = x + b * NSEQ;
  float v[4]; float mx = -1e30f;
  #pragma unroll
  for (int j = 0; j < 4; ++j){ v[j] = ip[j * 256 + tid]; mx = fmaxf(mx, v[j]); }
  mx = wave_max(mx);
  if ((tid & 63) == 0) red[tid >> 6] = mx;
  __syncthreads();
  mx = fmaxf(fmaxf(red[0], red[1]), fmaxf(red[2], red[3]));
  __syncthreads();
  float s = 0.f;
  #pragma unroll
  for (int j = 0; j < 4; ++j){ v[j] = __expf(v[j] - mx); s += v[j]; }
  s = wave_sum(s);
  if ((tid & 63) == 0) red[tid >> 6] = s;
  __syncthreads();
  s = red[0] + red[1] + red[2] + red[3];
  float inv = 1.0f / s;
  #pragma unroll
  for (int j = 0; j < 4; ++j) y[b * NSEQ + j * 256 + tid] = v[j] * inv;
}

__global__ __launch_bounds__(256) void k_ctx1(const float* __restrict__ alpha,
    const h16* __restrict__ h, float* __restrict__ part){
  int d = blockIdx.x * 256 + threadIdx.x;
  int b = blockIdx.y, pc = blockIdx.z;
  if (d >= DD) return;
  float acc = 0.f;
  const h16* hp = h + ((size_t)b * NSEQ + pc * 64) * DD + d;
  const float* ap = alpha + b * NSEQ + pc * 64;
  #pragma unroll 4
  for (int j = 0; j < 64; ++j) acc += ap[j] * (float)hp[(size_t)j * DD];
  part[(size_t)(b * 16 + pc) * DD + d] = acc;
}
__global__ __launch_bounds__(256) void k_ctx2(const float* __restrict__ part,
    float scale, float* __restrict__ ctx){
  int d = blockIdx.x * 256 + threadIdx.x;
  int b = blockIdx.y;
  if (d >= DD) return;
  float acc = 0.f;
  #pragma unroll
  for (int p = 0; p < 16; ++p) acc += part[(size_t)(b * 16 + p) * DD + d];
  ctx[b * DD + d] = acc * scale;
}

__global__ __launch_bounds__(256) void k_pool1(const float* __restrict__ x,
    float* __restrict__ part){
  int d = blockIdx.x * 256 + threadIdx.x;
  int b = blockIdx.y, pc = blockIdx.z;
  if (d >= DD) return;
  float acc = 0.f;
  const float* xp = x + ((size_t)b * NSEQ + pc * 64) * DD + d;
  #pragma unroll 4
  for (int j = 0; j < 64; ++j) acc += xp[(size_t)j * DD];
  part[(size_t)(b * 16 + pc) * DD + d] = acc;
}

__global__ __launch_bounds__(128) void k_clf(const float* __restrict__ pooled,
    const float* __restrict__ w1, const float* __restrict__ b1,
    const float* __restrict__ w2, const float* __restrict__ b2,
    float* __restrict__ out){
  __shared__ float pl[DD];
  __shared__ float h1[128];
  int b = blockIdx.x, tid = threadIdx.x;
  #pragma unroll
  for (int j = 0; j < 6; ++j) pl[j * 128 + tid] = pooled[b * DD + j * 128 + tid];
  __syncthreads();
  float acc = b1[tid];
  const float* wp = w1 + (size_t)tid * DD;
  for (int d = 0; d < DD; ++d) acc += pl[d] * wp[d];
  h1[tid] = gelu_f(acc);
  __syncthreads();
  if (tid < 2){
    float o = b2[tid];
    const float* w2p = w2 + tid * 128;
    for (int c = 0; c < 128; ++c) o += h1[c] * w2p[c];
    out[b * 2 + tid] = o;
  }
}

// =========================== launcher ===========================
static void gemmN(hipStream_t s, const h16* A, const h16* W, int M, int N, int K,
                  int lda, int ldw, int ldc, int Z,
                  long long sAh, long long sAl, long long sWh, long long sWl,
                  long long sCh, long long sCl, int bzs,
                  const float* bias, const float* sc, const float* off,
                  const h16* addh, float* outf, h16* outh){
  dim3 g(N/128, M/128, Z);
  k_gemm_h<128><<<g, 256, 0, s>>>(A, W, sAh, sAl, sWh, sWl, sCh, sCl,
                                  lda, ldw, ldc, K, bzs, bias, sc, off, addh, outf, outh);
}

extern "C" void kernel_launch(void* const* d_in, const int* in_sizes, int n_in,
                              void* d_out, int out_size, void* d_ws, size_t ws_size,
                              hipStream_t stream){
  (void)in_sizes; (void)n_in; (void)out_size;
  const float* w2v      = (const float*)d_in[0];
  const float* cqcc     = (const float*)d_in[1];
  const float* conv1_w  = (const float*)d_in[2];
  const float* conv1_b  = (const float*)d_in[3];
  const float* bn1_g    = (const float*)d_in[4];
  const float* bn1_b    = (const float*)d_in[5];
  const float* bn1_m    = (const float*)d_in[6];
  const float* bn1_v    = (const float*)d_in[7];
  const float* conv2_w  = (const float*)d_in[8];
  const float* conv2_b  = (const float*)d_in[9];
  const float* bn2_g    = (const float*)d_in[10];
  const float* bn2_b    = (const float*)d_in[11];
  const float* bn2_m    = (const float*)d_in[12];
  const float* bn2_v    = (const float*)d_in[13];
  const float* pos_embed= (const float*)d_in[14];
  const float* lnq_g    = (const float*)d_in[15];
  const float* lnq_b    = (const float*)d_in[16];
  const float* lnkv_g   = (const float*)d_in[17];
  const float* lnkv_b   = (const float*)d_in[18];
  const float* a1_in_w  = (const float*)d_in[19];
  const float* a1_in_b  = (const float*)d_in[20];
  const float* a1_out_w = (const float*)d_in[21];
  const float* a1_out_b = (const float*)d_in[22];
  const float* a2_in_w  = (const float*)d_in[23];
  const float* a2_in_b  = (const float*)d_in[24];
  const float* a2_out_w = (const float*)d_in[25];
  const float* a2_out_b = (const float*)d_in[26];
  const float* gat_fc_w = (const float*)d_in[27];
  const float* gat_fc_b = (const float*)d_in[28];
  const float* gat_a_w  = (const float*)d_in[29];
  // d_in[30] gat_a_b: cancels in softmax over j — unused.
  const float* gln_g    = (const float*)d_in[31];
  const float* gln_b    = (const float*)d_in[32];
  const float* clf_w1   = (const float*)d_in[33];
  const float* clf_b1   = (const float*)d_in[34];
  const float* clf_w2   = (const float*)d_in[35];
  const float* clf_b2   = (const float*)d_in[36];

  char* wsp = (char*)d_ws;
  auto F = [&](size_t bytes){ char* p = wsp; wsp += (bytes + 255) & ~(size_t)255; return p; };
  float* Abuf  = (float*)F(25165824);   // cq f32 -> xb
  float* Bbuf  = (float*)F(25165824);   // wpl f32 -> xh
  h16* Lq_cq   = (h16*)F(12582912);     // also A2 (im2col), also Ob
  h16* Lkv_cq  = (h16*)F(12582912);     // also x1 (conv1 f32)
  h16* Lq_w    = (h16*)F(12582912);
  h16* Lkv_w   = (h16*)F(12582912);     // also o1h
  h16* Qh      = (h16*)F(12582912);     // ┐
  h16* KVh     = (h16*)F(25165824);     // ├ x2f f32 (49.2 MB) spans these
  h16* VT      = (h16*)F(12582912);     // ┘
  h16* w_a1in  = (h16*)F(3538944);
  h16* w_a1out = (h16*)F(1179648);
  h16* w_a2in  = (h16*)F(3538944);
  h16* w_a2out = (h16*)F(1179648);
  h16* w_gat   = (h16*)F(3538944);
  h16* w_c2    = (h16*)F(589824);
  float* scb   = (float*)F(3072);
  float* offb  = (float*)F(3072);
  float* sj    = (float*)F(32768);
  float* alpha = (float*)F(32768);
  float* ctxb  = (float*)F(24576);
  float* pooled= (float*)F(24576);
  float* partb = (float*)F(393216);
  if ((size_t)(wsp - (char*)d_ws) > ws_size) return;

  float* x1  = (float*)Lkv_cq;     // conv1 out f32 (8.2 MB)
  h16*   A2  = Lq_cq;              // im2col (12.3 MB)
  float* x2f = (float*)Qh;         // conv2 out f32, spans Qh+KVh+VT
  h16*   Ob  = Lq_cq;              // attention out
  h16*   o1h = Lkv_w;              // MHA1 result
  float* xb  = Abuf;               // GAT running state f32
  h16*   xh  = (h16*)Bbuf;         // f16 copy
  h16*   hh  = Qh;                 // GAT h

  const size_t S = (size_t)BBATCH * NSEQ * DD;
  const int EW = (int)((S + 255) / 256);
  const int NR = BBATCH * NSEQ;    // 8192

  // --- weight casts + bn prep ---
  k_cast<<<(1769472+255)/256, 256, 0, stream>>>(a1_in_w,  w_a1in,  1769472);
  k_cast<<<(589824+255)/256,  256, 0, stream>>>(a1_out_w, w_a1out, 589824);
  k_cast<<<(1769472+255)/256, 256, 0, stream>>>(a2_in_w,  w_a2in,  1769472);
  k_cast<<<(589824+255)/256,  256, 0, stream>>>(a2_out_w, w_a2out, 589824);
  k_cast<<<(1769472+255)/256, 256, 0, stream>>>(gat_fc_w, w_gat,   1769472);
  k_cast<<<(294912+255)/256,  256, 0, stream>>>(conv2_w,  w_c2,    294912);
  k_bnprep<<<3, 256, 0, stream>>>(conv2_b, bn2_g, bn2_b, bn2_m, bn2_v, scb, offb);

  // --- front-end convs ---
  k_conv1t<<<dim3(8, 4, BBATCH), 256, 0, stream>>>(cqcc, conv1_w, conv1_b,
      bn1_g, bn1_b, bn1_m, bn1_v, x1);
  k_im2col<<<(16000*384+255)/256, 256, 0, stream>>>(x1, A2);
  gemmN(stream, A2, w_c2, 16000, DD, 384, 384, 384, DD, 1,
        0,0,0,0,0,0, 0, nullptr, scb, offb, nullptr, x2f, nullptr);
  k_interp2<<<EW, 256, 0, stream>>>(x2f, pos_embed, Abuf);
  k_addpos<<<EW, 256, 0, stream>>>(w2v, pos_embed, Bbuf);

  // --- all four LN variants in two passes ---
  k_ln2two<<<NR, 256, 0, stream>>>(Abuf, lnq_g, lnq_b, Lq_cq, lnkv_g, lnkv_b, Lkv_cq);
  k_ln2two<<<NR, 256, 0, stream>>>(Bbuf, lnq_g, lnq_b, Lq_w,  lnkv_g, lnkv_b, Lkv_w);

  dim3 gflash(32, 16);

  // ================= MHA1: q = LNq(cq), kv = LNkv(w) =================
  gemmN(stream, Lq_cq, w_a1in, NR, DD, DD, DD, DD, DD, 1, 0,0,0,0,0,0, 0,
        a1_in_b, nullptr, nullptr, nullptr, nullptr, Qh);
  gemmN(stream, Lkv_w, w_a1in + 589824, NR, DD, DD, DD, DD, 1536, 2,
        0,0, 0,589824, 0,768, DD,
        a1_in_b + DD, nullptr, nullptr, nullptr, nullptr, KVh);
  k_trV<<<dim3(32, 6, 32), 256, 0, stream>>>(KVh + 768, 1536, VT);
  k_flash<<<gflash, 256, 0, stream>>>(Qh, KVh, VT, Ob);
  gemmN(stream, Ob, w_a1out, NR, DD, DD, DD, DD, DD, 1, 0,0,0,0,0,0, 0,
        a1_out_b, nullptr, nullptr, nullptr, nullptr, o1h);

  // ================= MHA2: q = LNq(w), kv = LNkv(cq) =================
  gemmN(stream, Lq_w, w_a2in, NR, DD, DD, DD, DD, DD, 1, 0,0,0,0,0,0, 0,
        a2_in_b, nullptr, nullptr, nullptr, nullptr, Qh);
  gemmN(stream, Lkv_cq, w_a2in + 589824, NR, DD, DD, DD, DD, 1536, 2,
        0,0, 0,589824, 0,768, DD,
        a2_in_b + DD, nullptr, nullptr, nullptr, nullptr, KVh);
  k_trV<<<dim3(32, 6, 32), 256, 0, stream>>>(KVh + 768, 1536, VT);
  k_flash<<<gflash, 256, 0, stream>>>(Qh, KVh, VT, Ob);
  gemmN(stream, Ob, w_a2out, NR, DD, DD, DD, DD, DD, 1, 0,0,0,0,0,0, 0,
        a2_out_b, nullptr, nullptr, o1h, xb, xh);

  // ================= GAT x3 (softmax over j collapses) =================
  for (int l = 0; l < 3; ++l){
    gemmN(stream, xh, w_gat + (size_t)l*589824, NR, DD, DD, DD, DD, DD, 1,
          0,0,0,0,0,0, 0, gat_fc_b + l*DD, nullptr, nullptr, nullptr, nullptr, hh);
    k_rowdot<<<NR, 128, 0, stream>>>(hh, gat_a_w + l*2*DD + DD, sj);
    k_softmax1024<<<BBATCH, 256, 0, stream>>>(sj, alpha);
    k_ctx1<<<dim3(3, BBATCH, 16), 256, 0, stream>>>(alpha, hh, partb);
    k_ctx2<<<dim3(3, BBATCH), 256, 0, stream>>>(partb, 1.0f, ctxb);
    k_ln2<<<NR, 256, 0, stream>>>(xb, ctxb, gln_g + l*DD, gln_b + l*DD, xb, xh);
  }

  k_pool1<<<dim3(3, BBATCH, 16), 256, 0, stream>>>(xb, partb);
  k_ctx2<<<dim3(3, BBATCH), 256, 0, stream>>>(partb, 1.0f/NSEQ, pooled);
  k_clf<<<BBATCH, 128, 0, stream>>>(pooled, clf_w1, clf_b1, clf_w2, clf_b2,
                                    (float*)d_out);
}

// Round 7
// 696.621 us; speedup vs baseline: 1.0839x; 1.0839x over previous
//
#include <hip/hip_runtime.h>
#include <math.h>

#define DD 768
#define NH 4
#define HDIM 192
#define BBATCH 8
#define NSEQ 1024
#define TLEN 2000
#define SLOT 6291456   // 8192*768 elements

typedef _Float16 h16;
typedef _Float16 half8v __attribute__((ext_vector_type(8)));
typedef _Float16 half4v __attribute__((ext_vector_type(4)));
typedef float f32x4 __attribute__((ext_vector_type(4)));

__device__ __forceinline__ float gelu_f(float x){
  return 0.5f * x * (1.0f + erff(x * 0.70710678118654752440f));
}
__device__ __forceinline__ float wave_sum(float v){
  #pragma unroll
  for (int off = 32; off; off >>= 1) v += __shfl_xor(v, off);
  return v;
}
__device__ __forceinline__ float wave_max(float v){
  #pragma unroll
  for (int off = 32; off; off >>= 1) v = fmaxf(v, __shfl_xor(v, off));
  return v;
}
__device__ __forceinline__ void gload16(const h16* g, h16* l){
  __builtin_amdgcn_global_load_lds(
      (const __attribute__((address_space(1))) void*)g,
      (__attribute__((address_space(3))) void*)l, 16, 0, 0);
}
// m204 bijective XCD remap: physical block p (XCD = p%8) -> contiguous work chunk
__device__ __forceinline__ int xcd_remap(int orig, int nwg){
  int q = nwg >> 3, r = nwg & 7;
  int xcd = orig & 7, idx = orig >> 3;
  return (xcd < r ? xcd * (q + 1) : r * (q + 1) + (xcd - r) * q) + idx;
}

// ---------------- f32 -> f16 cast ----------------
__global__ __launch_bounds__(256) void k_cast(const float* __restrict__ s,
    h16* __restrict__ d, int n){
  int i = blockIdx.x * 256 + threadIdx.x;
  if (i < n) d[i] = (h16)s[i];
}

// ---------------- conv1 (20->128, k=3) + bn + gelu, LDS tiled ----------------
__global__ __launch_bounds__(256) void k_conv1t(const float* __restrict__ cqcc,
    const float* __restrict__ w, const float* __restrict__ bias,
    const float* __restrict__ g, const float* __restrict__ be,
    const float* __restrict__ mm, const float* __restrict__ vv,
    float* __restrict__ out){
  __shared__ float xs[20][258];
  __shared__ float wsm[32*60];
  const int t0 = blockIdx.x * 256;
  const int ocg = blockIdx.y, b = blockIdx.z;
  const int tid = threadIdx.x;
  for (int idx = tid; idx < 20*258; idx += 256){
    int ic = idx / 258, tt = idx % 258;
    int t = t0 + tt - 1;
    xs[ic][tt] = (t >= 0 && t < TLEN) ? cqcc[((size_t)b*20 + ic)*TLEN + t] : 0.f;
  }
  for (int idx = tid; idx < 32*60; idx += 256)
    wsm[idx] = w[ocg*32*60 + idx];
  __syncthreads();
  int t = t0 + tid;
  if (t >= TLEN) return;
  float acc[32] = {};
  for (int ic = 0; ic < 20; ++ic){
    float x0 = xs[ic][tid], x1v = xs[ic][tid+1], x2v = xs[ic][tid+2];
    #pragma unroll
    for (int oc = 0; oc < 32; ++oc){
      const float* wp = &wsm[(oc*20 + ic)*3];
      acc[oc] += wp[0]*x0 + wp[1]*x1v + wp[2]*x2v;
    }
  }
  #pragma unroll 4
  for (int oc = 0; oc < 32; ++oc){
    int c = ocg*32 + oc;
    float s = rsqrtf(vv[c] + 1e-5f) * g[c];
    float val = (acc[oc] + bias[c] - mm[c]) * s + be[c];
    out[((size_t)b*128 + c)*TLEN + t] = gelu_f(val);
  }
}

// ---------------- im2col for conv2: x1[b][128][2000] -> A2[16000][384] f16 ---
__global__ __launch_bounds__(256) void k_im2col(const float* __restrict__ x1,
    h16* __restrict__ A2){
  int idx = blockIdx.x * 256 + threadIdx.x;
  if (idx >= 16000*384) return;
  int c = idx % 384, m = idx / 384;
  int b = m / TLEN, t = m % TLEN;
  int ic = c / 3, kh = c % 3;
  int ts = t + kh - 1;
  float v = (ts < 0 || ts >= TLEN) ? 0.f : x1[((size_t)b*128 + ic)*TLEN + ts];
  A2[idx] = (h16)v;
}

// ---------------- BN epilogue constants for conv2 ----------------
__global__ void k_bnprep(const float* __restrict__ cb, const float* __restrict__ g,
    const float* __restrict__ be, const float* __restrict__ m,
    const float* __restrict__ v, float* __restrict__ sc, float* __restrict__ off){
  int i = blockIdx.x * 256 + threadIdx.x;
  if (i >= DD) return;
  float s = g[i] * rsqrtf(v[i] + 1e-5f);
  sc[i] = s;
  off[i] = (cb[i] - m[i]) * s + be[i];
}

// ---------------- interp (2000->1024) on [b][t][768] layout + pos ----------
__global__ __launch_bounds__(256) void k_interp2(const float* __restrict__ x2,
    const float* __restrict__ pe, float* __restrict__ cq){
  int idx = blockIdx.x * 256 + threadIdx.x;
  if (idx >= BBATCH * NSEQ * DD) return;
  int d = idx % DD; int i = (idx / DD) % NSEQ; int b = idx / (DD * NSEQ);
  float p = (i + 0.5f) * ((float)TLEN / (float)NSEQ) - 0.5f;
  p = fminf(fmaxf(p, 0.f), (float)(TLEN - 1));
  int lo = (int)floorf(p);
  int hi = min(lo + 1, TLEN - 1);
  float w = p - (float)lo;
  const float* base = x2 + (size_t)b * TLEN * DD + d;
  float val = base[(size_t)lo * DD] * (1.f - w) + base[(size_t)hi * DD] * w;
  cq[idx] = val + pe[(size_t)i * DD + d];
}

__global__ __launch_bounds__(256) void k_addpos(const float* __restrict__ x,
    const float* __restrict__ pe, float* __restrict__ y){
  int idx = blockIdx.x * 256 + threadIdx.x;
  if (idx >= BBATCH * NSEQ * DD) return;
  int d = idx % DD; int i = (idx / DD) % NSEQ;
  y[idx] = x[idx] + pe[(size_t)i * DD + d];
}

// ---------------- layernorm 768, optional ctx add, f32+f16 outputs ----------
__global__ __launch_bounds__(256) void k_ln2(const float* __restrict__ in,
    const float* __restrict__ ctx, const float* __restrict__ g,
    const float* __restrict__ be, float* __restrict__ outf, h16* __restrict__ outh){
  __shared__ float ss[4], sqq[4];
  int row = blockIdx.x, tid = threadIdx.x;
  const float* ip = in + (size_t)row * DD;
  int b = row >> 10;
  float v[3]; float s = 0.f, sq = 0.f;
  #pragma unroll
  for (int j = 0; j < 3; ++j){
    int d = j * 256 + tid;
    float x = ip[d];
    if (ctx) x += ctx[b * DD + d];
    v[j] = x; s += x; sq += x * x;
  }
  s = wave_sum(s); sq = wave_sum(sq);
  int w = tid >> 6;
  if ((tid & 63) == 0){ ss[w] = s; sqq[w] = sq; }
  __syncthreads();
  s  = ss[0] + ss[1] + ss[2] + ss[3];
  sq = sqq[0] + sqq[1] + sqq[2] + sqq[3];
  float mean = s * (1.f / DD);
  float var  = sq * (1.f / DD) - mean * mean;
  float r = rsqrtf(var + 1e-5f);
  #pragma unroll
  for (int j = 0; j < 3; ++j){
    int d = j * 256 + tid;
    float y = (v[j] - mean) * r * g[d] + be[d];
    if (outf) outf[(size_t)row * DD + d] = y;
    if (outh) outh[(size_t)row * DD + d] = (h16)y;
  }
}

// ---------------- dual layernorm: one read, two (g,b) variants --------------
__global__ __launch_bounds__(256) void k_ln2two(const float* __restrict__ in,
    const float* __restrict__ g1, const float* __restrict__ b1, h16* __restrict__ o1,
    const float* __restrict__ g2, const float* __restrict__ b2, h16* __restrict__ o2){
  __shared__ float ss[4], sqq[4];
  int row = blockIdx.x, tid = threadIdx.x;
  const float* ip = in + (size_t)row * DD;
  float v[3]; float s = 0.f, sq = 0.f;
  #pragma unroll
  for (int j = 0; j < 3; ++j){
    int d = j * 256 + tid;
    float x = ip[d];
    v[j] = x; s += x; sq += x * x;
  }
  s = wave_sum(s); sq = wave_sum(sq);
  int w = tid >> 6;
  if ((tid & 63) == 0){ ss[w] = s; sqq[w] = sq; }
  __syncthreads();
  s  = ss[0] + ss[1] + ss[2] + ss[3];
  sq = sqq[0] + sqq[1] + sqq[2] + sqq[3];
  float mean = s * (1.f / DD);
  float var  = sq * (1.f / DD) - mean * mean;
  float r = rsqrtf(var + 1e-5f);
  #pragma unroll
  for (int j = 0; j < 3; ++j){
    int d = j * 256 + tid;
    float xn = (v[j] - mean) * r;
    o1[(size_t)row * DD + d] = (h16)(xn * g1[d] + b1[d]);
    o2[(size_t)row * DD + d] = (h16)(xn * g2[d] + b2[d]);
  }
}

// ======== shared pipelined GEMM mainloop (BM=128, BN=64, BK=64) ========
// 3 LDS buffers, issue-ahead-2, counted vmcnt (6 loads/stage): T3/T4 pattern.
#define GEMM_MAINLOOP(Abase, lda, Wbase, ldw, Kdim)                          \
  auto stage = [&](int buf, int kt){                                         \
    _Pragma("unroll")                                                        \
    for (int i = 0; i < 4; ++i){                                             \
      int p = i*256 + tid; int row = p >> 3; int ch = (p & 7) ^ (row & 7);   \
      gload16(Abase + (size_t)(m0+row)*lda + kt + ch*8, &Als[buf][p*8]);     \
    }                                                                        \
    _Pragma("unroll")                                                        \
    for (int i = 0; i < 2; ++i){                                             \
      int p = i*256 + tid; int row = p >> 3; int ch = (p & 7) ^ (row & 7);   \
      gload16(Wbase + (size_t)(n0+row)*ldw + kt + ch*8, &Bls[buf][p*8]);     \
    }                                                                        \
  };                                                                         \
  stage(0, 0);                                                               \
  if (Kdim > 64) stage(1, 64);                                               \
  const int nk = Kdim >> 6;                                                  \
  for (int t = 0; t < nk; ++t){                                              \
    const int cur = t % 3;                                                   \
    if (t + 2 < nk){                                                         \
      stage((t + 2) % 3, (t + 2) << 6);                                      \
      asm volatile("s_waitcnt vmcnt(12)" ::: "memory");                      \
    } else if (t + 1 < nk){                                                  \
      asm volatile("s_waitcnt vmcnt(6)" ::: "memory");                       \
    } else {                                                                 \
      asm volatile("s_waitcnt vmcnt(0)" ::: "memory");                       \
    }                                                                        \
    __builtin_amdgcn_s_barrier();                                            \
    __builtin_amdgcn_sched_barrier(0);                                       \
    _Pragma("unroll")                                                        \
    for (int kk = 0; kk < 2; ++kk){                                          \
      half8v af[4], bf[2];                                                   \
      _Pragma("unroll")                                                      \
      for (int mi = 0; mi < 4; ++mi){                                        \
        int row = wr*64 + mi*16 + lr;                                        \
        int chp = (kk*4 + lg) ^ (row & 7);                                   \
        af[mi] = *(const half8v*)&Als[cur][row*64 + chp*8];                  \
      }                                                                      \
      _Pragma("unroll")                                                      \
      for (int ni = 0; ni < 2; ++ni){                                        \
        int row = wc*32 + ni*16 + lr;                                        \
        int chp = (kk*4 + lg) ^ (row & 7);                                   \
        bf[ni] = *(const half8v*)&Bls[cur][row*64 + chp*8];                  \
      }                                                                      \
      _Pragma("unroll")                                                      \
      for (int mi = 0; mi < 4; ++mi)                                         \
        _Pragma("unroll")                                                    \
        for (int ni = 0; ni < 2; ++ni)                                       \
          acc[mi][ni] = __builtin_amdgcn_mfma_f32_16x16x32_f16(              \
              af[mi], bf[ni], acc[mi][ni], 0, 0, 0);                         \
    }                                                                        \
    asm volatile("s_waitcnt lgkmcnt(0)" ::: "memory");                       \
    __builtin_amdgcn_sched_barrier(0);                                       \
    __builtin_amdgcn_s_barrier();                                            \
  }

// ---------------- general GEMM: C[M,N] = A[M,K] @ W[N,K]^T -------------------
__global__ __launch_bounds__(256) void k_gemm_h(
    const h16* __restrict__ A, const h16* __restrict__ W,
    int lda, int ldw, int ldc, int K,
    const float* __restrict__ bias, const float* __restrict__ sc,
    const float* __restrict__ off, const h16* __restrict__ addh,
    float* __restrict__ outf, h16* __restrict__ outh)
{
  __shared__ h16 Als[3][128*64];
  __shared__ h16 Bls[3][64*64];
  const int tid = threadIdx.x;
  const int gx = gridDim.x, gy = gridDim.y;
  const int wg = xcd_remap(blockIdx.x + gx * blockIdx.y, gx * gy);
  const int n0 = (wg % gx) * 64, m0 = (wg / gx) * 128;
  const int lane = tid & 63, wid = tid >> 6;
  const int wr = wid >> 1, wc = wid & 1;
  const int lr = lane & 15, lg = lane >> 4;
  f32x4 acc[4][2] = {};
  GEMM_MAINLOOP(A, lda, W, ldw, K)
  #pragma unroll
  for (int mi = 0; mi < 4; ++mi){
    #pragma unroll
    for (int ni = 0; ni < 2; ++ni){
      int col = n0 + wc*32 + ni*16 + lr;
      int rowb = m0 + wr*64 + mi*16 + lg*4;
      float cb = bias ? bias[col] : 0.f;
      #pragma unroll
      for (int r = 0; r < 4; ++r){
        size_t idx = (size_t)(rowb + r) * ldc + col;
        float v = acc[mi][ni][r];
        if (sc){ v = v * sc[col] + off[col]; v = gelu_f(v); }
        else v += cb;
        if (addh) v += (float)addh[idx];
        if (outf) outf[idx] = v;
        if (outh) outh[idx] = (h16)v;
      }
    }
  }
}

// ---------------- batched 6-way QKV projection GEMM --------------------------
// z: 0=Q1 1=K1 2=V1 3=Q2 4=K2 5=V2.  A slot from packed idx {0,3,3,2,1,1}.
__global__ __launch_bounds__(256) void k_gemm6(
    const h16* __restrict__ Lall, const h16* __restrict__ w6,
    const float* __restrict__ b1, const float* __restrict__ b2,
    h16* __restrict__ qkv6)
{
  __shared__ h16 Als[3][128*64];
  __shared__ h16 Bls[3][64*64];
  const int tid = threadIdx.x;
  const int gx = gridDim.x, gy = gridDim.y;   // 12, 64
  const int nwg = gx * gy * 6;
  const int wg = xcd_remap(blockIdx.x + gx*(blockIdx.y + gy*blockIdx.z), nwg);
  const int n0 = (wg % gx) * 64;
  const int m0 = ((wg / gx) % gy) * 128;
  const int bz = wg / (gx * gy);
  const int aidx = (1468 >> (2*bz)) & 3;      // {0,3,3,2,1,1}
  const h16* A = Lall + (size_t)aidx * SLOT;
  const h16* W = w6 + (size_t)bz * 589824;
  const float* bias = (bz < 3 ? b1 + bz*DD : b2 + (bz-3)*DD);
  h16* C = qkv6 + (size_t)bz * SLOT;
  const int lane = tid & 63, wid = tid >> 6;
  const int wr = wid >> 1, wc = wid & 1;
  const int lr = lane & 15, lg = lane >> 4;
  f32x4 acc[4][2] = {};
  GEMM_MAINLOOP(A, DD, W, DD, DD)
  #pragma unroll
  for (int mi = 0; mi < 4; ++mi){
    #pragma unroll
    for (int ni = 0; ni < 2; ++ni){
      int col = n0 + wc*32 + ni*16 + lr;
      int rowb = m0 + wr*64 + mi*16 + lg*4;
      float cb = bias[col];
      #pragma unroll
      for (int r = 0; r < 4; ++r)
        C[(size_t)(rowb + r) * DD + col] = (h16)(acc[mi][ni][r] + cb);
    }
  }
}

// ---------------- V transpose: V[b][q][h-part] -> VT[bh][d][q] ---------------
__global__ __launch_bounds__(256) void k_trV(const h16* __restrict__ Vh, int ldv,
    h16* __restrict__ VT){
  __shared__ h16 tile[32][36];
  const int z = blockIdx.z, b = z >> 2, h = z & 3;
  const int q0 = blockIdx.x * 32, d0 = blockIdx.y * 32;
  const int t = threadIdx.x;
  {
    int qq = t >> 3, dg = (t & 7) * 4;
    const h16* src = Vh + ((size_t)b*NSEQ + q0 + qq)*ldv + h*HDIM + d0 + dg;
    half4v v = *(const half4v*)src;
    *(half4v*)&tile[qq][dg] = v;
  }
  __syncthreads();
  {
    int dd = t >> 3, qg = (t & 7) * 4;
    half4v ov;
    ov[0] = tile[qg+0][dd]; ov[1] = tile[qg+1][dd];
    ov[2] = tile[qg+2][dd]; ov[3] = tile[qg+3][dd];
    *(half4v*)(VT + (size_t)z*HDIM*NSEQ + (size_t)(d0+dd)*NSEQ + q0 + qg) = ov;
  }
}

// ---------------- fused flash attention (MFMA, online softmax) ---------------
// grid (32 bh, 16 q-tiles): XCD-local K/V. Q in regs; K/V dbuf LDS, KVBLK=32.
__global__ __launch_bounds__(256) void k_flash(const h16* __restrict__ Qp,
    const h16* __restrict__ Kp, const h16* __restrict__ VTp,
    h16* __restrict__ Op){
  __shared__ h16 Ks[2][32*192];
  __shared__ h16 Vs[2][192*32];
  __shared__ h16 Ps[4][16*32];
  const int tid = threadIdx.x;
  const int bh = blockIdx.x, qt = blockIdx.y;
  const int b = bh >> 2, h = bh & 3;
  const int q0 = qt * 64;
  const h16* Qg = Qp + (size_t)b*NSEQ*DD + h*HDIM;
  const h16* Kg = Kp + (size_t)b*NSEQ*DD + h*HDIM;
  const h16* Vg = VTp + (size_t)bh*HDIM*NSEQ;
  const int lane = tid & 63, wid = tid >> 6;
  const int lr = lane & 15, lg = lane >> 4;
  half8v qf[6];
  {
    int qrow = q0 + wid*16 + lr;
    #pragma unroll
    for (int ks = 0; ks < 6; ++ks)
      qf[ks] = *(const half8v*)(Qg + (size_t)qrow*DD + ks*32 + lg*8);
  }
  auto stageK = [&](int buf, int k0){
    #pragma unroll
    for (int i = 0; i < 3; ++i){
      int p = i*256 + tid;              // 768 = 32 rows * 24 chunks
      int row = p / 24, chp = p % 24;
      int ch = chp ^ (row & 7);
      gload16(Kg + (size_t)(k0+row)*DD + ch*8, &Ks[buf][p*8]);
    }
  };
  auto stageV = [&](int buf, int k0){
    #pragma unroll
    for (int i = 0; i < 3; ++i){
      int p = i*256 + tid;              // 768 = 192 rows * 4 chunks
      int row = p >> 2, chp = p & 3;
      int ch = chp ^ ((row >> 1) & 3);
      gload16(Vg + (size_t)row*NSEQ + k0 + ch*8, &Vs[buf][p*8]);
    }
  };
  stageK(0, 0); stageV(0, 0);
  f32x4 oacc[12] = {};
  float m_run[4] = {-1e30f, -1e30f, -1e30f, -1e30f};
  float l_run[4] = {};
  const float SC = 0.07216878364870322f;   // 1/sqrt(192)
  __syncthreads();
  for (int kt = 0; kt < 32; ++kt){
    const int cur = kt & 1;
    if (kt + 1 < 32){ stageK(cur^1, (kt+1)*32); stageV(cur^1, (kt+1)*32); }
    f32x4 sacc[2] = {};
    #pragma unroll
    for (int ks = 0; ks < 6; ++ks){
      #pragma unroll
      for (int t = 0; t < 2; ++t){
        int krow = t*16 + lr;
        int ch = (ks*4 + lg) ^ (krow & 7);
        half8v kf = *(const half8v*)&Ks[cur][krow*192 + ch*8];
        sacc[t] = __builtin_amdgcn_mfma_f32_16x16x32_f16(qf[ks], kf, sacc[t], 0, 0, 0);
      }
    }
    float mnew[4], c[4], psum[4];
    #pragma unroll
    for (int r = 0; r < 4; ++r){
      float mt = fmaxf(sacc[0][r], sacc[1][r]);
      #pragma unroll
      for (int off = 1; off < 16; off <<= 1) mt = fmaxf(mt, __shfl_xor(mt, off));
      mnew[r] = fmaxf(m_run[r], mt * SC);
      c[r] = __expf(m_run[r] - mnew[r]);
      psum[r] = 0.f;
    }
    #pragma unroll
    for (int t = 0; t < 2; ++t){
      #pragma unroll
      for (int r = 0; r < 4; ++r){
        float p = __expf(sacc[t][r] * SC - mnew[r]);
        psum[r] += p;
        int q = lg*4 + r, key = t*16 + lr;
        int ch = (t*2 + (lr>>3)) ^ ((q>>1) & 3);
        Ps[wid][q*32 + ch*8 + (key & 7)] = (h16)p;
      }
    }
    #pragma unroll
    for (int r = 0; r < 4; ++r){
      #pragma unroll
      for (int off = 1; off < 16; off <<= 1) psum[r] += __shfl_xor(psum[r], off);
      l_run[r] = l_run[r] * c[r] + psum[r];
      m_run[r] = mnew[r];
    }
    #pragma unroll
    for (int dt = 0; dt < 12; ++dt){
      f32x4 o = oacc[dt];
      o[0] *= c[0]; o[1] *= c[1]; o[2] *= c[2]; o[3] *= c[3];
      oacc[dt] = o;
    }
    asm volatile("s_waitcnt lgkmcnt(0)" ::: "memory");
    {
      int pch = lg ^ ((lr >> 1) & 3);
      half8v pf = *(const half8v*)&Ps[wid][lr*32 + pch*8];
      #pragma unroll
      for (int dt = 0; dt < 12; ++dt){
        int drow = dt*16 + lr;
        int vch = lg ^ ((drow >> 1) & 3);
        half8v vf = *(const half8v*)&Vs[cur][drow*32 + vch*8];
        oacc[dt] = __builtin_amdgcn_mfma_f32_16x16x32_f16(pf, vf, oacc[dt], 0, 0, 0);
      }
    }
    __syncthreads();
  }
  float inv[4];
  #pragma unroll
  for (int r = 0; r < 4; ++r) inv[r] = 1.0f / l_run[r];
  h16* Og = Op + (size_t)b*NSEQ*DD + h*HDIM;
  #pragma unroll
  for (int dt = 0; dt < 12; ++dt){
    #pragma unroll
    for (int r = 0; r < 4; ++r){
      int q = q0 + wid*16 + lg*4 + r;
      Og[(size_t)q*DD + dt*16 + lr] = (h16)(oacc[dt][r] * inv[r]);
    }
  }
}

// ---------------- GAT helpers ----------------
__global__ __launch_bounds__(128) void k_rowdot(const h16* __restrict__ h,
    const float* __restrict__ aw, float* __restrict__ sj){
  __shared__ float red[2];
  int row = blockIdx.x, tid = threadIdx.x;
  float s = 0.f;
  if (tid < 96){
    half8v v = *(const half8v*)(h + (size_t)row * DD + tid*8);
    #pragma unroll
    for (int j = 0; j < 8; ++j) s += (float)v[j] * aw[tid*8 + j];
  }
  s = wave_sum(s);
  if ((tid & 63) == 0) red[tid >> 6] = s;
  __syncthreads();
  if (tid == 0) sj[row] = red[0] + red[1];
}

__global__ __launch_bounds__(256) void k_softmax1024(const float* __restrict__ x,
    float* __restrict__ y){
  __shared__ float red[4];
  int b = blockIdx.x, tid = threadIdx.x;
  const float* ip = x + b * NSEQ;
  float v[4]; float mx = -1e30f;
  #pragma unroll
  for (int j = 0; j < 4; ++j){ v[j] = ip[j * 256 + tid]; mx = fmaxf(mx, v[j]); }
  mx = wave_max(mx);
  if ((tid & 63) == 0) red[tid >> 6] = mx;
  __syncthreads();
  mx = fmaxf(fmaxf(red[0], red[1]), fmaxf(red[2], red[3]));
  __syncthreads();
  float s = 0.f;
  #pragma unroll
  for (int j = 0; j < 4; ++j){ v[j] = __expf(v[j] - mx); s += v[j]; }
  s = wave_sum(s);
  if ((tid & 63) == 0) red[tid >> 6] = s;
  __syncthreads();
  s = red[0] + red[1] + red[2] + red[3];
  float inv = 1.0f / s;
  #pragma unroll
  for (int j = 0; j < 4; ++j) y[b * NSEQ + j * 256 + tid] = v[j] * inv;
}

__global__ __launch_bounds__(256) void k_ctx1(const float* __restrict__ alpha,
    const h16* __restrict__ h, float* __restrict__ part){
  int d = blockIdx.x * 256 + threadIdx.x;
  int b = blockIdx.y, pc = blockIdx.z;
  if (d >= DD) return;
  float acc = 0.f;
  const h16* hp = h + ((size_t)b * NSEQ + pc * 64) * DD + d;
  const float* ap = alpha + b * NSEQ + pc * 64;
  #pragma unroll 4
  for (int j = 0; j < 64; ++j) acc += ap[j] * (float)hp[(size_t)j * DD];
  part[(size_t)(b * 16 + pc) * DD + d] = acc;
}
__global__ __launch_bounds__(256) void k_ctx2(const float* __restrict__ part,
    float scale, float* __restrict__ ctx){
  int d = blockIdx.x * 256 + threadIdx.x;
  int b = blockIdx.y;
  if (d >= DD) return;
  float acc = 0.f;
  #pragma unroll
  for (int p = 0; p < 16; ++p) acc += part[(size_t)(b * 16 + p) * DD + d];
  ctx[b * DD + d] = acc * scale;
}

__global__ __launch_bounds__(256) void k_pool1(const float* __restrict__ x,
    float* __restrict__ part){
  int d = blockIdx.x * 256 + threadIdx.x;
  int b = blockIdx.y, pc = blockIdx.z;
  if (d >= DD) return;
  float acc = 0.f;
  const float* xp = x + ((size_t)b * NSEQ + pc * 64) * DD + d;
  #pragma unroll 4
  for (int j = 0; j < 64; ++j) acc += xp[(size_t)j * DD];
  part[(size_t)(b * 16 + pc) * DD + d] = acc;
}

__global__ __launch_bounds__(128) void k_clf(const float* __restrict__ pooled,
    const float* __restrict__ w1, const float* __restrict__ b1,
    const float* __restrict__ w2, const float* __restrict__ b2,
    float* __restrict__ out){
  __shared__ float pl[DD];
  __shared__ float h1[128];
  int b = blockIdx.x, tid = threadIdx.x;
  #pragma unroll
  for (int j = 0; j < 6; ++j) pl[j * 128 + tid] = pooled[b * DD + j * 128 + tid];
  __syncthreads();
  float acc = b1[tid];
  const float* wp = w1 + (size_t)tid * DD;
  for (int d = 0; d < DD; ++d) acc += pl[d] * wp[d];
  h1[tid] = gelu_f(acc);
  __syncthreads();
  if (tid < 2){
    float o = b2[tid];
    const float* w2p = w2 + tid * 128;
    for (int c = 0; c < 128; ++c) o += h1[c] * w2p[c];
    out[b * 2 + tid] = o;
  }
}

// =========================== launcher ===========================
extern "C" void kernel_launch(void* const* d_in, const int* in_sizes, int n_in,
                              void* d_out, int out_size, void* d_ws, size_t ws_size,
                              hipStream_t stream){
  (void)in_sizes; (void)n_in; (void)out_size;
  const float* w2v      = (const float*)d_in[0];
  const float* cqcc     = (const float*)d_in[1];
  const float* conv1_w  = (const float*)d_in[2];
  const float* conv1_b  = (const float*)d_in[3];
  const float* bn1_g    = (const float*)d_in[4];
  const float* bn1_b    = (const float*)d_in[5];
  const float* bn1_m    = (const float*)d_in[6];
  const float* bn1_v    = (const float*)d_in[7];
  const float* conv2_w  = (const float*)d_in[8];
  const float* conv2_b  = (const float*)d_in[9];
  const float* bn2_g    = (const float*)d_in[10];
  const float* bn2_b    = (const float*)d_in[11];
  const float* bn2_m    = (const float*)d_in[12];
  const float* bn2_v    = (const float*)d_in[13];
  const float* pos_embed= (const float*)d_in[14];
  const float* lnq_g    = (const float*)d_in[15];
  const float* lnq_b    = (const float*)d_in[16];
  const float* lnkv_g   = (const float*)d_in[17];
  const float* lnkv_b   = (const float*)d_in[18];
  const float* a1_in_w  = (const float*)d_in[19];
  const float* a1_in_b  = (const float*)d_in[20];
  const float* a1_out_w = (const float*)d_in[21];
  const float* a1_out_b = (const float*)d_in[22];
  const float* a2_in_w  = (const float*)d_in[23];
  const float* a2_in_b  = (const float*)d_in[24];
  const float* a2_out_w = (const float*)d_in[25];
  const float* a2_out_b = (const float*)d_in[26];
  const float* gat_fc_w = (const float*)d_in[27];
  const float* gat_fc_b = (const float*)d_in[28];
  const float* gat_a_w  = (const float*)d_in[29];
  // d_in[30] gat_a_b: cancels in softmax over j — unused.
  const float* gln_g    = (const float*)d_in[31];
  const float* gln_b    = (const float*)d_in[32];
  const float* clf_w1   = (const float*)d_in[33];
  const float* clf_b1   = (const float*)d_in[34];
  const float* clf_w2   = (const float*)d_in[35];
  const float* clf_b2   = (const float*)d_in[36];

  char* wsp = (char*)d_ws;
  auto F = [&](size_t bytes){ char* p = wsp; wsp += (bytes + 255) & ~(size_t)255; return p; };
  float* Abuf  = (float*)F(25165824);     // cq f32 -> xb
  float* Bbuf  = (float*)F(25165824);     // wpl f32 -> xh
  h16* Lall    = (h16*)F(4*12582912);     // LN slots 0..3; also x1 (f32) + A2
  h16* qkv6    = (h16*)F(6*12582912);     // Q1 K1 V1 Q2 K2 V2; also x2f f32
  h16* VT      = (h16*)F(12582912);
  h16* o1h     = (h16*)F(12582912);
  h16* w6      = (h16*)F(2*3538944);      // Wqkv1 | Wqkv2
  h16* w_a1out = (h16*)F(1179648);
  h16* w_a2out = (h16*)F(1179648);
  h16* w_gat   = (h16*)F(3538944);
  h16* w_c2    = (h16*)F(589824);
  float* scb   = (float*)F(3072);
  float* offb  = (float*)F(3072);
  float* sj    = (float*)F(32768);
  float* alpha = (float*)F(32768);
  float* ctxb  = (float*)F(24576);
  float* pooled= (float*)F(24576);
  float* partb = (float*)F(393216);
  if ((size_t)(wsp - (char*)d_ws) > ws_size) return;

  float* x1  = (float*)Lall;              // conv1 out f32 (8.2 MB, slots 0-1 area)
  h16*   A2  = Lall + 2*SLOT;             // im2col (12.3 MB, slots 2-3 area)
  float* x2f = (float*)qkv6;              // conv2 out f32 (49.2 MB)
  float* xb  = Abuf;                      // GAT running state f32
  h16*   xh  = (h16*)Bbuf;                // f16 copy
  h16*   hh  = qkv6;                      // GAT h (slot0, dead after outproj2)

  const size_t S = (size_t)BBATCH * NSEQ * DD;
  const int EW = (int)((S + 255) / 256);
  const int NR = BBATCH * NSEQ;           // 8192

  // --- weight casts + bn prep ---
  k_cast<<<(1769472+255)/256, 256, 0, stream>>>(a1_in_w,  w6,           1769472);
  k_cast<<<(1769472+255)/256, 256, 0, stream>>>(a2_in_w,  w6 + 1769472, 1769472);
  k_cast<<<(589824+255)/256,  256, 0, stream>>>(a1_out_w, w_a1out, 589824);
  k_cast<<<(589824+255)/256,  256, 0, stream>>>(a2_out_w, w_a2out, 589824);
  k_cast<<<(1769472+255)/256, 256, 0, stream>>>(gat_fc_w, w_gat,   1769472);
  k_cast<<<(294912+255)/256,  256, 0, stream>>>(conv2_w,  w_c2,    294912);
  k_bnprep<<<3, 256, 0, stream>>>(conv2_b, bn2_g, bn2_b, bn2_m, bn2_v, scb, offb);

  // --- front-end convs ---
  k_conv1t<<<dim3(8, 4, BBATCH), 256, 0, stream>>>(cqcc, conv1_w, conv1_b,
      bn1_g, bn1_b, bn1_m, bn1_v, x1);
  k_im2col<<<(16000*384+255)/256, 256, 0, stream>>>(x1, A2);
  k_gemm_h<<<dim3(12, 125), 256, 0, stream>>>(A2, w_c2, 384, 384, DD, 384,
      nullptr, scb, offb, nullptr, x2f, nullptr);
  k_interp2<<<EW, 256, 0, stream>>>(x2f, pos_embed, Abuf);
  k_addpos<<<EW, 256, 0, stream>>>(w2v, pos_embed, Bbuf);

  // --- all four LN variants in two passes (slots 0..3) ---
  k_ln2two<<<NR, 256, 0, stream>>>(Abuf, lnq_g, lnq_b, Lall,
                                   lnkv_g, lnkv_b, Lall + SLOT);
  k_ln2two<<<NR, 256, 0, stream>>>(Bbuf, lnq_g, lnq_b, Lall + 2*SLOT,
                                   lnkv_g, lnkv_b, Lall + 3*SLOT);

  // --- all six QKV projections in one dispatch ---
  k_gemm6<<<dim3(12, 64, 6), 256, 0, stream>>>(Lall, w6, a1_in_b, a2_in_b, qkv6);

  dim3 gflash(32, 16);

  // ================= MHA1 =================
  k_trV<<<dim3(32, 6, 32), 256, 0, stream>>>(qkv6 + 2*(size_t)SLOT, DD, VT);
  k_flash<<<gflash, 256, 0, stream>>>(qkv6, qkv6 + (size_t)SLOT, VT, qkv6); // O1 -> slot0
  k_gemm_h<<<dim3(12, 64), 256, 0, stream>>>(qkv6, w_a1out, DD, DD, DD, DD,
      a1_out_b, nullptr, nullptr, nullptr, nullptr, o1h);

  // ================= MHA2 =================
  k_trV<<<dim3(32, 6, 32), 256, 0, stream>>>(qkv6 + 5*(size_t)SLOT, DD, VT);
  k_flash<<<gflash, 256, 0, stream>>>(qkv6 + 3*(size_t)SLOT, qkv6 + 4*(size_t)SLOT,
                                      VT, qkv6 + 3*(size_t)SLOT); // O2 -> slot3
  k_gemm_h<<<dim3(12, 64), 256, 0, stream>>>(qkv6 + 3*(size_t)SLOT, w_a2out,
      DD, DD, DD, DD, a2_out_b, nullptr, nullptr, o1h, xb, xh);

  // ================= GAT x3 (softmax over j collapses) =================
  for (int l = 0; l < 3; ++l){
    k_gemm_h<<<dim3(12, 64), 256, 0, stream>>>(xh, w_gat + (size_t)l*589824,
        DD, DD, DD, DD, gat_fc_b + l*DD, nullptr, nullptr, nullptr, nullptr, hh);
    k_rowdot<<<NR, 128, 0, stream>>>(hh, gat_a_w + l*2*DD + DD, sj);
    k_softmax1024<<<BBATCH, 256, 0, stream>>>(sj, alpha);
    k_ctx1<<<dim3(3, BBATCH, 16), 256, 0, stream>>>(alpha, hh, partb);
    k_ctx2<<<dim3(3, BBATCH), 256, 0, stream>>>(partb, 1.0f, ctxb);
    k_ln2<<<NR, 256, 0, stream>>>(xb, ctxb, gln_g + l*DD, gln_b + l*DD, xb, xh);
  }

  k_pool1<<<dim3(3, BBATCH, 16), 256, 0, stream>>>(xb, partb);
  k_ctx2<<<dim3(3, BBATCH), 256, 0, stream>>>(partb, 1.0f/NSEQ, pooled);
  k_clf<<<BBATCH, 128, 0, stream>>>(pooled, clf_w1, clf_b1, clf_w2, clf_b2,
                                    (float*)d_out);
}

// Round 8
// 644.548 us; speedup vs baseline: 1.1715x; 1.0808x over previous
//
#include <hip/hip_runtime.h>
#include <math.h>

#define DD 768
#define NH 4
#define HDIM 192
#define BBATCH 8
#define NSEQ 1024
#define TLEN 2000
#define SLOT 6291456   // 8192*768 elements

typedef _Float16 h16;
typedef _Float16 half8v __attribute__((ext_vector_type(8)));
typedef _Float16 half4v __attribute__((ext_vector_type(4)));
typedef float f32x4 __attribute__((ext_vector_type(4)));

__device__ __forceinline__ float gelu_f(float x){
  return 0.5f * x * (1.0f + erff(x * 0.70710678118654752440f));
}
__device__ __forceinline__ float wave_sum(float v){
  #pragma unroll
  for (int off = 32; off; off >>= 1) v += __shfl_xor(v, off);
  return v;
}
__device__ __forceinline__ float wave_max(float v){
  #pragma unroll
  for (int off = 32; off; off >>= 1) v = fmaxf(v, __shfl_xor(v, off));
  return v;
}
__device__ __forceinline__ void gload16(const h16* g, h16* l){
  __builtin_amdgcn_global_load_lds(
      (const __attribute__((address_space(1))) void*)g,
      (__attribute__((address_space(3))) void*)l, 16, 0, 0);
}
// m204 bijective XCD remap
__device__ __forceinline__ int xcd_remap(int orig, int nwg){
  int q = nwg >> 3, r = nwg & 7;
  int xcd = orig & 7, idx = orig >> 3;
  return (xcd < r ? xcd * (q + 1) : r * (q + 1) + (xcd - r) * q) + idx;
}

// ---------------- f32 -> f16 cast ----------------
__global__ __launch_bounds__(256) void k_cast(const float* __restrict__ s,
    h16* __restrict__ d, int n){
  int i = blockIdx.x * 256 + threadIdx.x;
  if (i < n) d[i] = (h16)s[i];
}

// ---------------- conv1 (20->128, k=3) + bn + gelu, LDS tiled ----------------
__global__ __launch_bounds__(256) void k_conv1t(const float* __restrict__ cqcc,
    const float* __restrict__ w, const float* __restrict__ bias,
    const float* __restrict__ g, const float* __restrict__ be,
    const float* __restrict__ mm, const float* __restrict__ vv,
    float* __restrict__ out){
  __shared__ float xs[20][258];
  __shared__ float wsm[32*60];
  const int t0 = blockIdx.x * 256;
  const int ocg = blockIdx.y, b = blockIdx.z;
  const int tid = threadIdx.x;
  for (int idx = tid; idx < 20*258; idx += 256){
    int ic = idx / 258, tt = idx % 258;
    int t = t0 + tt - 1;
    xs[ic][tt] = (t >= 0 && t < TLEN) ? cqcc[((size_t)b*20 + ic)*TLEN + t] : 0.f;
  }
  for (int idx = tid; idx < 32*60; idx += 256)
    wsm[idx] = w[ocg*32*60 + idx];
  __syncthreads();
  int t = t0 + tid;
  if (t >= TLEN) return;
  float acc[32] = {};
  for (int ic = 0; ic < 20; ++ic){
    float x0 = xs[ic][tid], x1v = xs[ic][tid+1], x2v = xs[ic][tid+2];
    #pragma unroll
    for (int oc = 0; oc < 32; ++oc){
      const float* wp = &wsm[(oc*20 + ic)*3];
      acc[oc] += wp[0]*x0 + wp[1]*x1v + wp[2]*x2v;
    }
  }
  #pragma unroll 4
  for (int oc = 0; oc < 32; ++oc){
    int c = ocg*32 + oc;
    float s = rsqrtf(vv[c] + 1e-5f) * g[c];
    float val = (acc[oc] + bias[c] - mm[c]) * s + be[c];
    out[((size_t)b*128 + c)*TLEN + t] = gelu_f(val);
  }
}

// ---------------- im2col for conv2: x1[b][128][2000] -> A2[16000][384] f16 ---
__global__ __launch_bounds__(256) void k_im2col(const float* __restrict__ x1,
    h16* __restrict__ A2){
  int idx = blockIdx.x * 256 + threadIdx.x;
  if (idx >= 16000*384) return;
  int c = idx % 384, m = idx / 384;
  int b = m / TLEN, t = m % TLEN;
  int ic = c / 3, kh = c % 3;
  int ts = t + kh - 1;
  float v = (ts < 0 || ts >= TLEN) ? 0.f : x1[((size_t)b*128 + ic)*TLEN + ts];
  A2[idx] = (h16)v;
}

// ---------------- BN epilogue constants for conv2 ----------------
__global__ void k_bnprep(const float* __restrict__ cb, const float* __restrict__ g,
    const float* __restrict__ be, const float* __restrict__ m,
    const float* __restrict__ v, float* __restrict__ sc, float* __restrict__ off){
  int i = blockIdx.x * 256 + threadIdx.x;
  if (i >= DD) return;
  float s = g[i] * rsqrtf(v[i] + 1e-5f);
  sc[i] = s;
  off[i] = (cb[i] - m[i]) * s + be[i];
}

// ------- fused interp(2000->1024)+pos + dual LN -> two f16 outputs ----------
__global__ __launch_bounds__(256) void k_interp_ln(const float* __restrict__ x2,
    const float* __restrict__ pe,
    const float* __restrict__ g1, const float* __restrict__ b1, h16* __restrict__ o1,
    const float* __restrict__ g2, const float* __restrict__ b2, h16* __restrict__ o2){
  __shared__ float ss[4], sqq[4];
  int row = blockIdx.x, tid = threadIdx.x;
  int b = row >> 10, i = row & 1023;
  float p = (i + 0.5f) * ((float)TLEN / (float)NSEQ) - 0.5f;
  p = fminf(fmaxf(p, 0.f), (float)(TLEN - 1));
  int lo = (int)floorf(p);
  int hi = min(lo + 1, TLEN - 1);
  float w = p - (float)lo;
  const float* blo = x2 + ((size_t)b * TLEN + lo) * DD;
  const float* bhi = x2 + ((size_t)b * TLEN + hi) * DD;
  const float* per = pe + (size_t)i * DD;
  float v[3]; float s = 0.f, sq = 0.f;
  #pragma unroll
  for (int j = 0; j < 3; ++j){
    int d = j * 256 + tid;
    float x = blo[d] * (1.f - w) + bhi[d] * w + per[d];
    v[j] = x; s += x; sq += x * x;
  }
  s = wave_sum(s); sq = wave_sum(sq);
  int wv = tid >> 6;
  if ((tid & 63) == 0){ ss[wv] = s; sqq[wv] = sq; }
  __syncthreads();
  s  = ss[0] + ss[1] + ss[2] + ss[3];
  sq = sqq[0] + sqq[1] + sqq[2] + sqq[3];
  float mean = s * (1.f / DD);
  float var  = sq * (1.f / DD) - mean * mean;
  float r = rsqrtf(var + 1e-5f);
  #pragma unroll
  for (int j = 0; j < 3; ++j){
    int d = j * 256 + tid;
    float xn = (v[j] - mean) * r;
    o1[(size_t)row * DD + d] = (h16)(xn * g1[d] + b1[d]);
    o2[(size_t)row * DD + d] = (h16)(xn * g2[d] + b2[d]);
  }
}

// ------- fused w2v+pos + dual LN -> two f16 outputs --------------------------
__global__ __launch_bounds__(256) void k_addpos_ln(const float* __restrict__ xin,
    const float* __restrict__ pe,
    const float* __restrict__ g1, const float* __restrict__ b1, h16* __restrict__ o1,
    const float* __restrict__ g2, const float* __restrict__ b2, h16* __restrict__ o2){
  __shared__ float ss[4], sqq[4];
  int row = blockIdx.x, tid = threadIdx.x;
  int i = row & 1023;
  const float* ip = xin + (size_t)row * DD;
  const float* per = pe + (size_t)i * DD;
  float v[3]; float s = 0.f, sq = 0.f;
  #pragma unroll
  for (int j = 0; j < 3; ++j){
    int d = j * 256 + tid;
    float x = ip[d] + per[d];
    v[j] = x; s += x; sq += x * x;
  }
  s = wave_sum(s); sq = wave_sum(sq);
  int wv = tid >> 6;
  if ((tid & 63) == 0){ ss[wv] = s; sqq[wv] = sq; }
  __syncthreads();
  s  = ss[0] + ss[1] + ss[2] + ss[3];
  sq = sqq[0] + sqq[1] + sqq[2] + sqq[3];
  float mean = s * (1.f / DD);
  float var  = sq * (1.f / DD) - mean * mean;
  float r = rsqrtf(var + 1e-5f);
  #pragma unroll
  for (int j = 0; j < 3; ++j){
    int d = j * 256 + tid;
    float xn = (v[j] - mean) * r;
    o1[(size_t)row * DD + d] = (h16)(xn * g1[d] + b1[d]);
    o2[(size_t)row * DD + d] = (h16)(xn * g2[d] + b2[d]);
  }
}

// ---------------- layernorm 768, optional ctx add, f32+f16 outputs ----------
__global__ __launch_bounds__(256) void k_ln2(const float* __restrict__ in,
    const float* __restrict__ ctx, const float* __restrict__ g,
    const float* __restrict__ be, float* __restrict__ outf, h16* __restrict__ outh){
  __shared__ float ss[4], sqq[4];
  int row = blockIdx.x, tid = threadIdx.x;
  const float* ip = in + (size_t)row * DD;
  int b = row >> 10;
  float v[3]; float s = 0.f, sq = 0.f;
  #pragma unroll
  for (int j = 0; j < 3; ++j){
    int d = j * 256 + tid;
    float x = ip[d];
    if (ctx) x += ctx[b * DD + d];
    v[j] = x; s += x; sq += x * x;
  }
  s = wave_sum(s); sq = wave_sum(sq);
  int w = tid >> 6;
  if ((tid & 63) == 0){ ss[w] = s; sqq[w] = sq; }
  __syncthreads();
  s  = ss[0] + ss[1] + ss[2] + ss[3];
  sq = sqq[0] + sqq[1] + sqq[2] + sqq[3];
  float mean = s * (1.f / DD);
  float var  = sq * (1.f / DD) - mean * mean;
  float r = rsqrtf(var + 1e-5f);
  #pragma unroll
  for (int j = 0; j < 3; ++j){
    int d = j * 256 + tid;
    float y = (v[j] - mean) * r * g[d] + be[d];
    if (outf) outf[(size_t)row * DD + d] = y;
    if (outh) outh[(size_t)row * DD + d] = (h16)y;
  }
}

// ======== pipelined GEMM mainloop (BM=128, BN=128, BK=64) ========
// 2 LDS buffers, issue-ahead-1, counted vmcnt(8) (8 loads/thread/stage).
#define GEMM_MAINLOOP(Abase, lda, Wbase, ldw, Kdim)                          \
  auto stage = [&](int buf, int kt){                                         \
    _Pragma("unroll")                                                        \
    for (int i = 0; i < 4; ++i){                                             \
      int p = i*256 + tid; int row = p >> 3; int ch = (p & 7) ^ (row & 7);   \
      gload16(Abase + (size_t)(m0+row)*lda + kt + ch*8, &Als[buf][p*8]);     \
    }                                                                        \
    _Pragma("unroll")                                                        \
    for (int i = 0; i < 4; ++i){                                             \
      int p = i*256 + tid; int row = p >> 3; int ch = (p & 7) ^ (row & 7);   \
      gload16(Wbase + (size_t)(n0+row)*ldw + kt + ch*8, &Bls[buf][p*8]);     \
    }                                                                        \
  };                                                                         \
  stage(0, 0);                                                               \
  const int nk = Kdim >> 6;                                                  \
  for (int t = 0; t < nk; ++t){                                              \
    const int cur = t & 1;                                                   \
    if (t + 1 < nk){                                                         \
      stage(cur ^ 1, (t + 1) << 6);                                          \
      asm volatile("s_waitcnt vmcnt(8)" ::: "memory");                       \
    } else {                                                                 \
      asm volatile("s_waitcnt vmcnt(0)" ::: "memory");                       \
    }                                                                        \
    __builtin_amdgcn_s_barrier();                                            \
    __builtin_amdgcn_sched_barrier(0);                                       \
    __builtin_amdgcn_s_setprio(1);                                           \
    _Pragma("unroll")                                                        \
    for (int kk = 0; kk < 2; ++kk){                                          \
      half8v af[4], bf[4];                                                   \
      _Pragma("unroll")                                                      \
      for (int mi = 0; mi < 4; ++mi){                                        \
        int row = wr*64 + mi*16 + lr;                                        \
        int chp = (kk*4 + lg) ^ (row & 7);                                   \
        af[mi] = *(const half8v*)&Als[cur][row*64 + chp*8];                  \
      }                                                                      \
      _Pragma("unroll")                                                      \
      for (int ni = 0; ni < 4; ++ni){                                        \
        int row = wc*64 + ni*16 + lr;                                        \
        int chp = (kk*4 + lg) ^ (row & 7);                                   \
        bf[ni] = *(const half8v*)&Bls[cur][row*64 + chp*8];                  \
      }                                                                      \
      _Pragma("unroll")                                                      \
      for (int mi = 0; mi < 4; ++mi)                                         \
        _Pragma("unroll")                                                    \
        for (int ni = 0; ni < 4; ++ni)                                       \
          acc[mi][ni] = __builtin_amdgcn_mfma_f32_16x16x32_f16(              \
              af[mi], bf[ni], acc[mi][ni], 0, 0, 0);                         \
    }                                                                        \
    __builtin_amdgcn_s_setprio(0);                                           \
    asm volatile("s_waitcnt lgkmcnt(0)" ::: "memory");                       \
    __builtin_amdgcn_sched_barrier(0);                                       \
    __builtin_amdgcn_s_barrier();                                            \
  }

// ---------------- general GEMM: C[M,N] = A[M,K] @ W[N,K]^T -------------------
__global__ __launch_bounds__(256) void k_gemm_h(
    const h16* __restrict__ A, const h16* __restrict__ W,
    int lda, int ldw, int ldc, int K,
    const float* __restrict__ bias, const float* __restrict__ sc,
    const float* __restrict__ off, const h16* __restrict__ addh,
    float* __restrict__ outf, h16* __restrict__ outh)
{
  __shared__ h16 Als[2][128*64];
  __shared__ h16 Bls[2][128*64];
  const int tid = threadIdx.x;
  const int gx = gridDim.x, gy = gridDim.y;
  const int wg = xcd_remap(blockIdx.x + gx * blockIdx.y, gx * gy);
  const int n0 = (wg % gx) * 128, m0 = (wg / gx) * 128;
  const int lane = tid & 63, wid = tid >> 6;
  const int wr = wid >> 1, wc = wid & 1;
  const int lr = lane & 15, lg = lane >> 4;
  f32x4 acc[4][4] = {};
  GEMM_MAINLOOP(A, lda, W, ldw, K)
  #pragma unroll
  for (int mi = 0; mi < 4; ++mi){
    #pragma unroll
    for (int ni = 0; ni < 4; ++ni){
      int col = n0 + wc*64 + ni*16 + lr;
      int rowb = m0 + wr*64 + mi*16 + lg*4;
      float cb = bias ? bias[col] : 0.f;
      #pragma unroll
      for (int r = 0; r < 4; ++r){
        size_t idx = (size_t)(rowb + r) * ldc + col;
        float v = acc[mi][ni][r];
        if (sc){ v = v * sc[col] + off[col]; v = gelu_f(v); }
        else v += cb;
        if (addh) v += (float)addh[idx];
        if (outf) outf[idx] = v;
        if (outh) outh[idx] = (h16)v;
      }
    }
  }
}

// ---------------- batched 6-way QKV projection GEMM --------------------------
// z: 0=Q1 1=K1 2=V1 3=Q2 4=K2 5=V2.  A slot from packed idx {0,3,3,2,1,1}.
__global__ __launch_bounds__(256) void k_gemm6(
    const h16* __restrict__ Lall, const h16* __restrict__ w6,
    const float* __restrict__ b1, const float* __restrict__ b2,
    h16* __restrict__ qkv6)
{
  __shared__ h16 Als[2][128*64];
  __shared__ h16 Bls[2][128*64];
  const int tid = threadIdx.x;
  const int gx = gridDim.x, gy = gridDim.y;   // 6, 64
  const int nwg = gx * gy * 6;
  const int wg = xcd_remap(blockIdx.x + gx*(blockIdx.y + gy*blockIdx.z), nwg);
  const int n0 = (wg % gx) * 128;
  const int m0 = ((wg / gx) % gy) * 128;
  const int bz = wg / (gx * gy);
  const int aidx = (1468 >> (2*bz)) & 3;      // {0,3,3,2,1,1}
  const h16* A = Lall + (size_t)aidx * SLOT;
  const h16* W = w6 + (size_t)bz * 589824;
  const float* bias = (bz < 3 ? b1 + bz*DD : b2 + (bz-3)*DD);
  h16* C = qkv6 + (size_t)bz * SLOT;
  const int lane = tid & 63, wid = tid >> 6;
  const int wr = wid >> 1, wc = wid & 1;
  const int lr = lane & 15, lg = lane >> 4;
  f32x4 acc[4][4] = {};
  GEMM_MAINLOOP(A, DD, W, DD, DD)
  #pragma unroll
  for (int mi = 0; mi < 4; ++mi){
    #pragma unroll
    for (int ni = 0; ni < 4; ++ni){
      int col = n0 + wc*64 + ni*16 + lr;
      int rowb = m0 + wr*64 + mi*16 + lg*4;
      float cb = bias[col];
      #pragma unroll
      for (int r = 0; r < 4; ++r)
        C[(size_t)(rowb + r) * DD + col] = (h16)(acc[mi][ni][r] + cb);
    }
  }
}

// ---------------- V transpose: V[b][q][h-part] -> VT[bh][d][q] ---------------
__global__ __launch_bounds__(256) void k_trV(const h16* __restrict__ Vh, int ldv,
    h16* __restrict__ VT){
  __shared__ h16 tile[32][36];
  const int z = blockIdx.z, b = z >> 2, h = z & 3;
  const int q0 = blockIdx.x * 32, d0 = blockIdx.y * 32;
  const int t = threadIdx.x;
  {
    int qq = t >> 3, dg = (t & 7) * 4;
    const h16* src = Vh + ((size_t)b*NSEQ + q0 + qq)*ldv + h*HDIM + d0 + dg;
    half4v v = *(const half4v*)src;
    *(half4v*)&tile[qq][dg] = v;
  }
  __syncthreads();
  {
    int dd = t >> 3, qg = (t & 7) * 4;
    half4v ov;
    ov[0] = tile[qg+0][dd]; ov[1] = tile[qg+1][dd];
    ov[2] = tile[qg+2][dd]; ov[3] = tile[qg+3][dd];
    *(half4v*)(VT + (size_t)z*HDIM*NSEQ + (size_t)(d0+dd)*NSEQ + q0 + qg) = ov;
  }
}

// ---------------- fused flash attention (MFMA, online softmax) ---------------
// grid (32 bh, 16 q-tiles): XCD-local K/V. Q in regs; K/V dbuf LDS, KVBLK=32.
__global__ __launch_bounds__(256) void k_flash(const h16* __restrict__ Qp,
    const h16* __restrict__ Kp, const h16* __restrict__ VTp,
    h16* __restrict__ Op){
  __shared__ h16 Ks[2][32*192];
  __shared__ h16 Vs[2][192*32];
  __shared__ h16 Ps[4][16*32];
  const int tid = threadIdx.x;
  const int bh = blockIdx.x, qt = blockIdx.y;
  const int b = bh >> 2, h = bh & 3;
  const int q0 = qt * 64;
  const h16* Qg = Qp + (size_t)b*NSEQ*DD + h*HDIM;
  const h16* Kg = Kp + (size_t)b*NSEQ*DD + h*HDIM;
  const h16* Vg = VTp + (size_t)bh*HDIM*NSEQ;
  const int lane = tid & 63, wid = tid >> 6;
  const int lr = lane & 15, lg = lane >> 4;
  half8v qf[6];
  {
    int qrow = q0 + wid*16 + lr;
    #pragma unroll
    for (int ks = 0; ks < 6; ++ks)
      qf[ks] = *(const half8v*)(Qg + (size_t)qrow*DD + ks*32 + lg*8);
  }
  auto stageK = [&](int buf, int k0){
    #pragma unroll
    for (int i = 0; i < 3; ++i){
      int p = i*256 + tid;              // 768 = 32 rows * 24 chunks
      int row = p / 24, chp = p % 24;
      int ch = chp ^ (row & 7);
      gload16(Kg + (size_t)(k0+row)*DD + ch*8, &Ks[buf][p*8]);
    }
  };
  auto stageV = [&](int buf, int k0){
    #pragma unroll
    for (int i = 0; i < 3; ++i){
      int p = i*256 + tid;              // 768 = 192 rows * 4 chunks
      int row = p >> 2, chp = p & 3;
      int ch = chp ^ ((row >> 1) & 3);
      gload16(Vg + (size_t)row*NSEQ + k0 + ch*8, &Vs[buf][p*8]);
    }
  };
  stageK(0, 0); stageV(0, 0);
  f32x4 oacc[12] = {};
  float m_run[4] = {-1e30f, -1e30f, -1e30f, -1e30f};
  float l_run[4] = {};
  const float SC = 0.07216878364870322f;   // 1/sqrt(192)
  __syncthreads();
  for (int kt = 0; kt < 32; ++kt){
    const int cur = kt & 1;
    if (kt + 1 < 32){ stageK(cur^1, (kt+1)*32); stageV(cur^1, (kt+1)*32); }
    f32x4 sacc[2] = {};
    __builtin_amdgcn_s_setprio(1);
    #pragma unroll
    for (int ks = 0; ks < 6; ++ks){
      #pragma unroll
      for (int t = 0; t < 2; ++t){
        int krow = t*16 + lr;
        int ch = (ks*4 + lg) ^ (krow & 7);
        half8v kf = *(const half8v*)&Ks[cur][krow*192 + ch*8];
        sacc[t] = __builtin_amdgcn_mfma_f32_16x16x32_f16(qf[ks], kf, sacc[t], 0, 0, 0);
      }
    }
    __builtin_amdgcn_s_setprio(0);
    float mnew[4], c[4], psum[4];
    #pragma unroll
    for (int r = 0; r < 4; ++r){
      float mt = fmaxf(sacc[0][r], sacc[1][r]);
      #pragma unroll
      for (int off = 1; off < 16; off <<= 1) mt = fmaxf(mt, __shfl_xor(mt, off));
      mnew[r] = fmaxf(m_run[r], mt * SC);
      c[r] = __expf(m_run[r] - mnew[r]);
      psum[r] = 0.f;
    }
    #pragma unroll
    for (int t = 0; t < 2; ++t){
      #pragma unroll
      for (int r = 0; r < 4; ++r){
        float p = __expf(sacc[t][r] * SC - mnew[r]);
        psum[r] += p;
        int q = lg*4 + r, key = t*16 + lr;
        int ch = (t*2 + (lr>>3)) ^ ((q>>1) & 3);
        Ps[wid][q*32 + ch*8 + (key & 7)] = (h16)p;
      }
    }
    #pragma unroll
    for (int r = 0; r < 4; ++r){
      #pragma unroll
      for (int off = 1; off < 16; off <<= 1) psum[r] += __shfl_xor(psum[r], off);
      l_run[r] = l_run[r] * c[r] + psum[r];
      m_run[r] = mnew[r];
    }
    #pragma unroll
    for (int dt = 0; dt < 12; ++dt){
      f32x4 o = oacc[dt];
      o[0] *= c[0]; o[1] *= c[1]; o[2] *= c[2]; o[3] *= c[3];
      oacc[dt] = o;
    }
    asm volatile("s_waitcnt lgkmcnt(0)" ::: "memory");
    __builtin_amdgcn_sched_barrier(0);
    {
      int pch = lg ^ ((lr >> 1) & 3);
      half8v pf = *(const half8v*)&Ps[wid][lr*32 + pch*8];
      __builtin_amdgcn_s_setprio(1);
      #pragma unroll
      for (int dt = 0; dt < 12; ++dt){
        int drow = dt*16 + lr;
        int vch = lg ^ ((drow >> 1) & 3);
        half8v vf = *(const half8v*)&Vs[cur][drow*32 + vch*8];
        oacc[dt] = __builtin_amdgcn_mfma_f32_16x16x32_f16(pf, vf, oacc[dt], 0, 0, 0);
      }
      __builtin_amdgcn_s_setprio(0);
    }
    __syncthreads();
  }
  float inv[4];
  #pragma unroll
  for (int r = 0; r < 4; ++r) inv[r] = 1.0f / l_run[r];
  h16* Og = Op + (size_t)b*NSEQ*DD + h*HDIM;
  #pragma unroll
  for (int dt = 0; dt < 12; ++dt){
    #pragma unroll
    for (int r = 0; r < 4; ++r){
      int q = q0 + wid*16 + lg*4 + r;
      Og[(size_t)q*DD + dt*16 + lr] = (h16)(oacc[dt][r] * inv[r]);
    }
  }
}

// ---------------- GAT helpers ----------------
__global__ __launch_bounds__(128) void k_rowdot(const h16* __restrict__ h,
    const float* __restrict__ aw, float* __restrict__ sj){
  __shared__ float red[2];
  int row = blockIdx.x, tid = threadIdx.x;
  float s = 0.f;
  if (tid < 96){
    half8v v = *(const half8v*)(h + (size_t)row * DD + tid*8);
    #pragma unroll
    for (int j = 0; j < 8; ++j) s += (float)v[j] * aw[tid*8 + j];
  }
  s = wave_sum(s);
  if ((tid & 63) == 0) red[tid >> 6] = s;
  __syncthreads();
  if (tid == 0) sj[row] = red[0] + red[1];
}

__global__ __launch_bounds__(256) void k_softmax1024(const float* __restrict__ x,
    float* __restrict__ y){
  __shared__ float red[4];
  int b = blockIdx.x, tid = threadIdx.x;
  const float* ip = x + b * NSEQ;
  float v[4]; float mx = -1e30f;
  #pragma unroll
  for (int j = 0; j < 4; ++j){ v[j] = ip[j * 256 + tid]; mx = fmaxf(mx, v[j]); }
  mx = wave_max(mx);
  if ((tid & 63) == 0) red[tid >> 6] = mx;
  __syncthreads();
  mx = fmaxf(fmaxf(red[0], red[1]), fmaxf(red[2], red[3]));
  __syncthreads();
  float s = 0.f;
  #pragma unroll
  for (int j = 0; j < 4; ++j){ v[j] = __expf(v[j] - mx); s += v[j]; }
  s = wave_sum(s);
  if ((tid & 63) == 0) red[tid >> 6] = s;
  __syncthreads();
  s = red[0] + red[1] + red[2] + red[3];
  float inv = 1.0f / s;
  #pragma unroll
  for (int j = 0; j < 4; ++j) y[b * NSEQ + j * 256 + tid] = v[j] * inv;
}

__global__ __launch_bounds__(256) void k_ctx1(const float* __restrict__ alpha,
    const h16* __restrict__ h, float* __restrict__ part){
  int d = blockIdx.x * 256 + threadIdx.x;
  int b = blockIdx.y, pc = blockIdx.z;
  if (d >= DD) return;
  float acc = 0.f;
  const h16* hp = h + ((size_t)b * NSEQ + pc * 64) * DD + d;
  const float* ap = alpha + b * NSEQ + pc * 64;
  #pragma unroll 4
  for (int j = 0; j < 64; ++j) acc += ap[j] * (float)hp[(size_t)j * DD];
  part[(size_t)(b * 16 + pc) * DD + d] = acc;
}
__global__ __launch_bounds__(256) void k_ctx2(const float* __restrict__ part,
    float scale, float* __restrict__ ctx){
  int d = blockIdx.x * 256 + threadIdx.x;
  int b = blockIdx.y;
  if (d >= DD) return;
  float acc = 0.f;
  #pragma unroll
  for (int p = 0; p < 16; ++p) acc += part[(size_t)(b * 16 + p) * DD + d];
  ctx[b * DD + d] = acc * scale;
}

__global__ __launch_bounds__(256) void k_pool1(const float* __restrict__ x,
    float* __restrict__ part){
  int d = blockIdx.x * 256 + threadIdx.x;
  int b = blockIdx.y, pc = blockIdx.z;
  if (d >= DD) return;
  float acc = 0.f;
  const float* xp = x + ((size_t)b * NSEQ + pc * 64) * DD + d;
  #pragma unroll 4
  for (int j = 0; j < 64; ++j) acc += xp[(size_t)j * DD];
  part[(size_t)(b * 16 + pc) * DD + d] = acc;
}

__global__ __launch_bounds__(128) void k_clf(const float* __restrict__ pooled,
    const float* __restrict__ w1, const float* __restrict__ b1,
    const float* __restrict__ w2, const float* __restrict__ b2,
    float* __restrict__ out){
  __shared__ float pl[DD];
  __shared__ float h1[128];
  int b = blockIdx.x, tid = threadIdx.x;
  #pragma unroll
  for (int j = 0; j < 6; ++j) pl[j * 128 + tid] = pooled[b * DD + j * 128 + tid];
  __syncthreads();
  float acc = b1[tid];
  const float* wp = w1 + (size_t)tid * DD;
  for (int d = 0; d < DD; ++d) acc += pl[d] * wp[d];
  h1[tid] = gelu_f(acc);
  __syncthreads();
  if (tid < 2){
    float o = b2[tid];
    const float* w2p = w2 + tid * 128;
    for (int c = 0; c < 128; ++c) o += h1[c] * w2p[c];
    out[b * 2 + tid] = o;
  }
}

// =========================== launcher ===========================
extern "C" void kernel_launch(void* const* d_in, const int* in_sizes, int n_in,
                              void* d_out, int out_size, void* d_ws, size_t ws_size,
                              hipStream_t stream){
  (void)in_sizes; (void)n_in; (void)out_size;
  const float* w2v      = (const float*)d_in[0];
  const float* cqcc     = (const float*)d_in[1];
  const float* conv1_w  = (const float*)d_in[2];
  const float* conv1_b  = (const float*)d_in[3];
  const float* bn1_g    = (const float*)d_in[4];
  const float* bn1_b    = (const float*)d_in[5];
  const float* bn1_m    = (const float*)d_in[6];
  const float* bn1_v    = (const float*)d_in[7];
  const float* conv2_w  = (const float*)d_in[8];
  const float* conv2_b  = (const float*)d_in[9];
  const float* bn2_g    = (const float*)d_in[10];
  const float* bn2_b    = (const float*)d_in[11];
  const float* bn2_m    = (const float*)d_in[12];
  const float* bn2_v    = (const float*)d_in[13];
  const float* pos_embed= (const float*)d_in[14];
  const float* lnq_g    = (const float*)d_in[15];
  const float* lnq_b    = (const float*)d_in[16];
  const float* lnkv_g   = (const float*)d_in[17];
  const float* lnkv_b   = (const float*)d_in[18];
  const float* a1_in_w  = (const float*)d_in[19];
  const float* a1_in_b  = (const float*)d_in[20];
  const float* a1_out_w = (const float*)d_in[21];
  const float* a1_out_b = (const float*)d_in[22];
  const float* a2_in_w  = (const float*)d_in[23];
  const float* a2_in_b  = (const float*)d_in[24];
  const float* a2_out_w = (const float*)d_in[25];
  const float* a2_out_b = (const float*)d_in[26];
  const float* gat_fc_w = (const float*)d_in[27];
  const float* gat_fc_b = (const float*)d_in[28];
  const float* gat_a_w  = (const float*)d_in[29];
  // d_in[30] gat_a_b: cancels in softmax over j — unused.
  const float* gln_g    = (const float*)d_in[31];
  const float* gln_b    = (const float*)d_in[32];
  const float* clf_w1   = (const float*)d_in[33];
  const float* clf_b1   = (const float*)d_in[34];
  const float* clf_w2   = (const float*)d_in[35];
  const float* clf_b2   = (const float*)d_in[36];

  char* wsp = (char*)d_ws;
  auto F = [&](size_t bytes){ char* p = wsp; wsp += (bytes + 255) & ~(size_t)255; return p; };
  float* Abuf  = (float*)F(25165824);     // xb (GAT state, f32)
  float* Bbuf  = (float*)F(25165824);     // xh (f16 copy, first half)
  h16* Lall    = (h16*)F(4*12582912);     // LN slots 0..3; also x1 (f32) + A2
  h16* qkv6    = (h16*)F(6*12582912);     // Q1 K1 V1 Q2 K2 V2; also x2f f32
  h16* VT      = (h16*)F(12582912);
  h16* o1h     = (h16*)F(12582912);
  h16* w6      = (h16*)F(2*3538944);      // Wqkv1 | Wqkv2
  h16* w_a1out = (h16*)F(1179648);
  h16* w_a2out = (h16*)F(1179648);
  h16* w_gat   = (h16*)F(3538944);
  h16* w_c2    = (h16*)F(589824);
  float* scb   = (float*)F(3072);
  float* offb  = (float*)F(3072);
  float* sj    = (float*)F(32768);
  float* alpha = (float*)F(32768);
  float* ctxb  = (float*)F(24576);
  float* pooled= (float*)F(24576);
  float* partb = (float*)F(393216);
  if ((size_t)(wsp - (char*)d_ws) > ws_size) return;

  float* x1  = (float*)Lall;              // conv1 out f32 (8.2 MB)
  h16*   A2  = Lall + 2*SLOT;             // im2col (12.3 MB)
  float* x2f = (float*)qkv6;              // conv2 out f32 (49.2 MB)
  float* xb  = Abuf;                      // GAT running state f32
  h16*   xh  = (h16*)Bbuf;                // f16 copy
  h16*   hh  = qkv6;                      // GAT h (slot0, dead after outproj2)

  const int NR = BBATCH * NSEQ;           // 8192

  // --- weight casts + bn prep ---
  k_cast<<<(1769472+255)/256, 256, 0, stream>>>(a1_in_w,  w6,           1769472);
  k_cast<<<(1769472+255)/256, 256, 0, stream>>>(a2_in_w,  w6 + 1769472, 1769472);
  k_cast<<<(589824+255)/256,  256, 0, stream>>>(a1_out_w, w_a1out, 589824);
  k_cast<<<(589824+255)/256,  256, 0, stream>>>(a2_out_w, w_a2out, 589824);
  k_cast<<<(1769472+255)/256, 256, 0, stream>>>(gat_fc_w, w_gat,   1769472);
  k_cast<<<(294912+255)/256,  256, 0, stream>>>(conv2_w,  w_c2,    294912);
  k_bnprep<<<3, 256, 0, stream>>>(conv2_b, bn2_g, bn2_b, bn2_m, bn2_v, scb, offb);

  // --- front-end convs ---
  k_conv1t<<<dim3(8, 4, BBATCH), 256, 0, stream>>>(cqcc, conv1_w, conv1_b,
      bn1_g, bn1_b, bn1_m, bn1_v, x1);
  k_im2col<<<(16000*384+255)/256, 256, 0, stream>>>(x1, A2);
  k_gemm_h<<<dim3(6, 125), 256, 0, stream>>>(A2, w_c2, 384, 384, DD, 384,
      nullptr, scb, offb, nullptr, x2f, nullptr);

  // --- fused interp/addpos + dual LN (slots 0..3) ---
  k_interp_ln<<<NR, 256, 0, stream>>>(x2f, pos_embed,
      lnq_g, lnq_b, Lall, lnkv_g, lnkv_b, Lall + SLOT);
  k_addpos_ln<<<NR, 256, 0, stream>>>(w2v, pos_embed,
      lnq_g, lnq_b, Lall + 2*SLOT, lnkv_g, lnkv_b, Lall + 3*SLOT);

  // --- all six QKV projections in one dispatch ---
  k_gemm6<<<dim3(6, 64, 6), 256, 0, stream>>>(Lall, w6, a1_in_b, a2_in_b, qkv6);

  dim3 gflash(32, 16);

  // ================= MHA1 =================
  k_trV<<<dim3(32, 6, 32), 256, 0, stream>>>(qkv6 + 2*(size_t)SLOT, DD, VT);
  k_flash<<<gflash, 256, 0, stream>>>(qkv6, qkv6 + (size_t)SLOT, VT, qkv6); // O1 -> slot0
  k_gemm_h<<<dim3(6, 64), 256, 0, stream>>>(qkv6, w_a1out, DD, DD, DD, DD,
      a1_out_b, nullptr, nullptr, nullptr, nullptr, o1h);

  // ================= MHA2 =================
  k_trV<<<dim3(32, 6, 32), 256, 0, stream>>>(qkv6 + 5*(size_t)SLOT, DD, VT);
  k_flash<<<gflash, 256, 0, stream>>>(qkv6 + 3*(size_t)SLOT, qkv6 + 4*(size_t)SLOT,
                                      VT, qkv6 + 3*(size_t)SLOT); // O2 -> slot3
  k_gemm_h<<<dim3(6, 64), 256, 0, stream>>>(qkv6 + 3*(size_t)SLOT, w_a2out,
      DD, DD, DD, DD, a2_out_b, nullptr, nullptr, o1h, xb, xh);

  // ================= GAT x3 (softmax over j collapses) =================
  for (int l = 0; l < 3; ++l){
    k_gemm_h<<<dim3(6, 64), 256, 0, stream>>>(xh, w_gat + (size_t)l*589824,
        DD, DD, DD, DD, gat_fc_b + l*DD, nullptr, nullptr, nullptr, nullptr, hh);
    k_rowdot<<<NR, 128, 0, stream>>>(hh, gat_a_w + l*2*DD + DD, sj);
    k_softmax1024<<<BBATCH, 256, 0, stream>>>(sj, alpha);
    k_ctx1<<<dim3(3, BBATCH, 16), 256, 0, stream>>>(alpha, hh, partb);
    k_ctx2<<<dim3(3, BBATCH), 256, 0, stream>>>(partb, 1.0f, ctxb);
    k_ln2<<<NR, 256, 0, stream>>>(xb, ctxb, gln_g + l*DD, gln_b + l*DD, xb, xh);
  }

  k_pool1<<<dim3(3, BBATCH, 16), 256, 0, stream>>>(xb, partb);
  k_ctx2<<<dim3(3, BBATCH), 256, 0, stream>>>(partb, 1.0f/NSEQ, pooled);
  k_clf<<<BBATCH, 128, 0, stream>>>(pooled, clf_w1, clf_b1, clf_w2, clf_b2,
                                    (float*)d_out);
}